// Round 2
// baseline (693.440 us; speedup 1.0000x reference)
//
#include <hip/hip_runtime.h>
#include <hip/hip_bf16.h>

// Problem constants
#define B_   8192
#define C_   1024
#define H_   16
#define M_   (B_ * 4)      // 32768 rows
#define K_   1024
#define N1_  3072          // qkv GEMM cols
// SCALE = 0.125 folded into W_qkvT q-section. fp8 weights pre-scaled x32,
// compensated by MX scale byte 122 (=2^-5).

typedef __attribute__((ext_vector_type(8))) short short8;
typedef __attribute__((ext_vector_type(4))) float f32x4;
typedef __attribute__((ext_vector_type(8))) int   int8v;

__device__ __forceinline__ unsigned short f2bf(float f) {
  union { float f; unsigned u; } v; v.f = f;
  unsigned r = v.u + 0x7fffu + ((v.u >> 16) & 1u);   // RNE
  return (unsigned short)(r >> 16);
}
__device__ __forceinline__ float bf2f(unsigned short u) {
  union { unsigned u; float f; } v; v.u = ((unsigned)u) << 16;
  return v.f;
}
__device__ __forceinline__ int pk_fp8(float a, float b, float c, float d) {
  int r = __builtin_amdgcn_cvt_pk_fp8_f32(a, b, 0, false);
  r = __builtin_amdgcn_cvt_pk_fp8_f32(c, d, r, true);
  return r;
}

// ---- cast x: fp8 (scale 1.0) for GEMM1  +  bf16 rows n in {1,2} for fixup ----
__global__ __launch_bounds__(256) void cast_x_k(const float* __restrict__ x,
                                                unsigned char* __restrict__ x8,
                                                unsigned short* __restrict__ xsel) {
  const int row = blockIdx.x;               // 32768 rows (b*4+n)
  const int tid = threadIdx.x;
  float4 v = ((const float4*)(x + (size_t)row * 1024))[tid];
  ((int*)(x8 + (size_t)row * 1024))[tid] = pk_fp8(v.x, v.y, v.z, v.w);
  const int n = row & 3;
  if (n == 1 || n == 2) {                   // wave-uniform branch (per row)
    ushort4 o;
    o.x = f2bf(v.x); o.y = f2bf(v.y); o.z = f2bf(v.z); o.w = f2bf(v.w);
    ((ushort4*)(xsel + ((size_t)(n - 1) * 8192 + (row >> 2)) * 1024))[tid] = o;
  }
}

// ---- transpose W_qkv [1024,3072] -> [3072,1024]: bf16 (fixup B) + fp8 x32 ----
__global__ __launch_bounds__(256) void transpose_wqkv_k(const float* __restrict__ in,
                                                        unsigned short* __restrict__ outb,
                                                        unsigned char* __restrict__ out8) {
  __shared__ float t[32][33];
  int tx = threadIdx.x, ty = threadIdx.y;   // block (32,8)
  int j0 = blockIdx.x * 32, c0 = blockIdx.y * 32;
#pragma unroll
  for (int i = 0; i < 4; ++i)
    t[ty + i * 8][tx] = in[(size_t)(c0 + ty + i * 8) * N1_ + j0 + tx];
  __syncthreads();
#pragma unroll
  for (int i = 0; i < 4; ++i) {
    int j = j0 + ty + i * 8;
    float v = t[tx][ty + i * 8];
    if (j < 1024) v *= 0.125f;              // SCALE folded into q rows
    outb[(size_t)j * K_ + c0 + tx] = f2bf(v);
    out8[(size_t)j * K_ + c0 + tx] =
        (unsigned char)(__builtin_amdgcn_cvt_pk_fp8_f32(v * 32.f, v * 32.f, 0, false) & 0xff);
  }
}

// ---- cast W_proj -> fp8 x32 (no transpose: NT GEMM uses W rows as-is) --------
__global__ __launch_bounds__(256) void cast_wproj_k(const float* __restrict__ in,
                                                    unsigned char* __restrict__ out) {
  int i = blockIdx.x * 256 + threadIdx.x;
  float4 v = ((const float4*)in)[i];
  ((int*)out)[i] = pk_fp8(v.x * 32.f, v.y * 32.f, v.z * 32.f, v.w * 32.f);
}

// ---- bf16 NT GEMM (m97 structure) for the attn_sel fixup rows ----------------
// A = xsel [16384,1024]; rows <8192 use Wq section, >=8192 use Wk section.
// B-fragments load DIRECTLY global->reg (weight panel is L2-resident); only A
// is staged through LDS. Halves the LDS-pipe traffic (the measured limiter).
__global__ __launch_bounds__(256) void gemm_fixup(const unsigned short* __restrict__ A,
                                                  const unsigned short* __restrict__ B0,
                                                  unsigned short* __restrict__ Cbf) {
  __shared__ unsigned short lsA[128 * 32];
  const int K = 1024, Ncols = 1024;
  const int tid = threadIdx.x;
  const int wave = tid >> 6, lane = tid & 63;
  const int wm = (wave >> 1) * 64, wn = (wave & 1) * 64;
  const long tile_m = (long)blockIdx.y * 128, tile_n = (long)blockIdx.x * 128;
  const unsigned short* Bm = B0 + (tile_m >= 8192 ? (size_t)1024 * 1024 : 0);

  f32x4 acc[4][4] = {};
  const int ci0 = (wave * 2 + 0) * 64 + lane;
  const int ci1 = (wave * 2 + 1) * 64 + lane;
  const int r0 = ci0 >> 2, kc0 = (ci0 & 3) * 8;
  const int r1 = ci1 >> 2, kc1 = (ci1 & 3) * 8;
  const unsigned short* gA0 = A + (tile_m + r0) * K + kc0;
  const unsigned short* gA1 = A + (tile_m + r1) * K + kc1;
  unsigned short* dA0 = lsA + (wave * 2 + 0) * 512;
  unsigned short* dA1 = lsA + (wave * 2 + 1) * 512;
  const int r16 = lane & 15, q8 = (lane >> 4) * 8;
  // direct-global B fragment base: row = tile_n + wn + ni*16 + r16
  const unsigned short* gBf = Bm + (size_t)(tile_n + wn + r16) * K + q8;

  for (int kt = 0; kt < K; kt += 32) {
    __builtin_amdgcn_global_load_lds((const __attribute__((address_space(1))) void*)(gA0 + kt),
                                     (__attribute__((address_space(3))) void*)dA0, 16, 0, 0);
    __builtin_amdgcn_global_load_lds((const __attribute__((address_space(1))) void*)(gA1 + kt),
                                     (__attribute__((address_space(3))) void*)dA1, 16, 0, 0);
    short8 bfr[4];
#pragma unroll
    for (int ni = 0; ni < 4; ++ni)
      bfr[ni] = *(const short8*)(gBf + (size_t)ni * 16 * K + kt);
    __syncthreads();   // drains vmcnt: A staged AND B frags in regs
    short8 afr[4];
#pragma unroll
    for (int mi = 0; mi < 4; ++mi)
      afr[mi] = *(const short8*)&lsA[(wm + mi * 16 + r16) * 32 + q8];
#pragma unroll
    for (int mi = 0; mi < 4; ++mi)
#pragma unroll
      for (int ni = 0; ni < 4; ++ni)
        acc[mi][ni] = __builtin_amdgcn_mfma_f32_16x16x32_bf16(afr[mi], bfr[ni], acc[mi][ni], 0, 0, 0);
    __syncthreads();
  }
  const int cl = lane & 15, rq = (lane >> 4) * 4;
#pragma unroll
  for (int mi = 0; mi < 4; ++mi)
#pragma unroll
    for (int ni = 0; ni < 4; ++ni) {
      long col = tile_n + wn + ni * 16 + cl;
#pragma unroll
      for (int r = 0; r < 4; ++r) {
        long row = tile_m + wm + mi * 16 + rq + r;
        Cbf[(size_t)row * Ncols + col] = f2bf(acc[mi][ni][r]);
      }
    }
}

// ---- MX-fp8 NT GEMM: C[m,n] = (2^(sA-127))(2^(sB-127)) sum_k A[m,k]B[n,k] ----
// 128x128 tile, BK=128, mfma_scale_f32_16x16x128_f8f6f4, fp8 e4m3.
// A staged via global_load_lds with the verified XOR swizzle (global-side
// scatter, linear LDS dest). B-fragments load DIRECTLY global->reg: the weight
// panel (<=3 MB) is L2/L3-resident across the 256 M-tiles, and removing B from
// LDS halves the LDS-pipe traffic (staging-write + frag-read), which the
// round-0/1 counters showed to be the limiter (MfmaUtil ~25%, LDS-pipe ~2x
// oversubscribed vs MFMA).
template <int OUTMODE>  // 0: bf16 C   1: fp32 C + bias
__global__ __launch_bounds__(256) void gemm_mx(const unsigned char* __restrict__ A,
                                               const unsigned char* __restrict__ Bm,
                                               unsigned short* __restrict__ Cbf,
                                               float* __restrict__ Cf,
                                               const float* __restrict__ bias,
                                               int K, int Ncols, int sA, int sB) {
  __shared__ unsigned char lsA[16384];
  const int tid = threadIdx.x;
  const int wave = tid >> 6, lane = tid & 63;
  const int wm = (wave >> 1) * 64, wn = (wave & 1) * 64;
  const long tile_m = (long)blockIdx.y * 128, tile_n = (long)blockIdx.x * 128;

  f32x4 acc[4][4] = {};

  // staging: 4 A-chunks of 16B per thread per k-iter (swizzle on global side)
  size_t offA[4];
#pragma unroll
  for (int j = 0; j < 4; ++j) {
    int ci = j * 256 + tid;
    int qg = ci >> 8, id = ci & 255;
    int r2 = (id >> 3) & 1, r3 = (id >> 4) & 1;
    int rr0 = ((id >> 1) & 1) ^ r2, rr1 = ((id >> 2) & 1) ^ r3;
    int row = rr0 | (rr1 << 1) | (r2 << 2) | (r3 << 3) | ((id >> 5) << 4);
    int half = (id & 1) ^ rr0;
    offA[j] = (size_t)(tile_m + row) * K + qg * 32 + half * 16;
  }

  const int hl = lane & 15, qg = lane >> 4;
  const int swz = (hl & 12) << 3;
  const int laneFragBase = qg * 4096 + ((hl * 32) ^ swz) + ((hl & 1) << 4);
  // direct-global B fragment base: row = tile_n + wn + ni*16 + hl, k-chunk qg
  const unsigned char* gBf = Bm + (size_t)(tile_n + wn + hl) * K + qg * 32;

  for (int kt = 0; kt < K; kt += 128) {
#pragma unroll
    for (int j = 0; j < 4; ++j)
      __builtin_amdgcn_global_load_lds(
          (const __attribute__((address_space(1))) void*)(A + offA[j] + kt),
          (__attribute__((address_space(3))) void*)(lsA + (j * 256 + wave * 64) * 16), 16, 0, 0);

    // B fragments: 2x dwordx4 per ni, natural k-half order
    int8v bfr[4];
#pragma unroll
    for (int ni = 0; ni < 4; ++ni) {
      const unsigned char* bp = gBf + (size_t)ni * 16 * K + kt;
      int4 h0 = *(const int4*)bp;
      int4 h1 = *(const int4*)(bp + 16);
      bfr[ni] = int8v{h0.x, h0.y, h0.z, h0.w, h1.x, h1.y, h1.z, h1.w};
    }
    __syncthreads();   // drains vmcnt: A staged AND B frags in regs

    int8v af[4];
#pragma unroll
    for (int mi = 0; mi < 4; ++mi) {
      int ad = (wm + mi * 16) * 32 + laneFragBase;
      int4 h0 = *(const int4*)(lsA + ad);
      int4 h1 = *(const int4*)(lsA + (ad ^ 16));
      af[mi] = int8v{h0.x, h0.y, h0.z, h0.w, h1.x, h1.y, h1.z, h1.w};
    }
#pragma unroll
    for (int mi = 0; mi < 4; ++mi)
#pragma unroll
      for (int ni = 0; ni < 4; ++ni)
        acc[mi][ni] = __builtin_amdgcn_mfma_scale_f32_16x16x128_f8f6f4(
            af[mi], bfr[ni], acc[mi][ni], 0, 0, 0, sA, 0, sB);
    __syncthreads();
  }

  const int cl = lane & 15, rq = (lane >> 4) * 4;
#pragma unroll
  for (int mi = 0; mi < 4; ++mi)
#pragma unroll
    for (int ni = 0; ni < 4; ++ni) {
      long col = tile_n + wn + ni * 16 + cl;
      float bv = (OUTMODE == 1) ? bias[col] : 0.f;
#pragma unroll
      for (int r = 0; r < 4; ++r) {
        long row = tile_m + wm + mi * 16 + rq + r;
        if (OUTMODE == 0)
          Cbf[(size_t)row * Ncols + col] = f2bf(acc[mi][ni][r]);
        else
          Cf[(size_t)row * Ncols + col] = acc[mi][ni][r] + bv;
      }
    }
}

// ---- MFMA attention: 1 wave = 1 batch; attn_sel from accurate bf16 q1/k2 -----
__global__ __launch_bounds__(256) void attn_mfma_k(const unsigned short* __restrict__ qkv,
                                                   const unsigned short* __restrict__ q1,
                                                   const unsigned short* __restrict__ k2,
                                                   const float* __restrict__ WE,
                                                   const float* __restrict__ WF,
                                                   unsigned char* __restrict__ hmid8,
                                                   float* __restrict__ attn_sel) {
  __shared__ float As[4][16 * 17 + 2];
  const int tid = threadIdx.x;
  const int wave = tid >> 6, lane = tid & 63;
  const int b = blockIdx.x * 4 + wave;
  const size_t qb = (size_t)b * 4 * N1_;
  const int hl = lane & 15, qg = lane >> 4;

  // S[n][m] products (fp8-derived qkv: fine, softmax path is insensitive)
  f32x4 accS[4][4] = {};
  f32x4 accSel = {};
#pragma unroll
  for (int ch = 0; ch < 2; ++ch) {
    const int off = ch * 32 + qg * 8;
    short8 qf[4], kf[4];
#pragma unroll
    for (int n = 0; n < 4; ++n)
      qf[n] = *(const short8*)(qkv + qb + (size_t)n * N1_ + 0 + hl * 64 + off);
#pragma unroll
    for (int m = 0; m < 4; ++m)
      kf[m] = *(const short8*)(qkv + qb + (size_t)m * N1_ + 1024 + hl * 64 + off);
#pragma unroll
    for (int n = 0; n < 4; ++n)
#pragma unroll
      for (int m = 0; m < 4; ++m)
        accS[n][m] = __builtin_amdgcn_mfma_f32_16x16x32_bf16(qf[n], kf[m], accS[n][m], 0, 0, 0);
    // accurate attn_sel from bf16 fixup rows
    short8 qs = *(const short8*)(q1 + (size_t)b * 1024 + hl * 64 + off);
    short8 ks = *(const short8*)(k2 + (size_t)b * 1024 + hl * 64 + off);
    accSel = __builtin_amdgcn_mfma_f32_16x16x32_bf16(qs, ks, accSel, 0, 0, 0);
  }

#pragma unroll
  for (int r = 0; r < 4; ++r)
    attn_sel[(size_t)b * 256 + (qg * 4 + r) * 16 + hl] = 1.f / (1.f + __expf(-accSel[r]));

  if ((hl >> 2) == qg) {   // diagonal lanes: per-head softmax + A' = attn.WF
    const int h = hl, rr = h & 3;
    float Sm[4][4];
#pragma unroll
    for (int n = 0; n < 4; ++n)
#pragma unroll
      for (int m = 0; m < 4; ++m) Sm[n][m] = accS[n][m][rr];
#pragma unroll
    for (int n = 0; n < 4; ++n) {
      float lg[4];
#pragma unroll
      for (int p = 0; p < 4; ++p)
        lg[p] = Sm[n][0] * WE[p * 4] + Sm[n][1] * WE[p * 4 + 1] +
                Sm[n][2] * WE[p * 4 + 2] + Sm[n][3] * WE[p * 4 + 3];
      float mx = fmaxf(fmaxf(lg[0], lg[1]), fmaxf(lg[2], lg[3]));
      float e0 = __expf(lg[0] - mx), e1 = __expf(lg[1] - mx);
      float e2 = __expf(lg[2] - mx), e3 = __expf(lg[3] - mx);
      float inv = 1.f / (e0 + e1 + e2 + e3);
      e0 *= inv; e1 *= inv; e2 *= inv; e3 *= inv;
#pragma unroll
      for (int m = 0; m < 4; ++m)
        As[wave][h * 17 + n * 4 + m] =
            e0 * WF[0 * 4 + m] + e1 * WF[1 * 4 + m] + e2 * WF[2 * 4 + m] + e3 * WF[3 * 4 + m];
    }
  }
  __syncthreads();

  {  // out[h,n,d] = sum_m A'[n,m] v[h,m,d]; write hmid as fp8 x32 (scale 122)
    const int h = lane & 15, dg = lane >> 4;
    float Ap[4][4];
#pragma unroll
    for (int n = 0; n < 4; ++n)
#pragma unroll
      for (int m = 0; m < 4; ++m) Ap[n][m] = As[wave][h * 17 + n * 4 + m];

    float outv[4][16] = {};
#pragma unroll
    for (int m = 0; m < 4; ++m) {
      const unsigned short* vp = qkv + qb + (size_t)m * N1_ + 2048 + h * 64 + dg * 16;
      short8 v0 = *(const short8*)(vp);
      short8 v1 = *(const short8*)(vp + 8);
      float vf[16];
#pragma unroll
      for (int j = 0; j < 8; ++j) {
        vf[j] = bf2f((unsigned short)v0[j]);
        vf[8 + j] = bf2f((unsigned short)v1[j]);
      }
#pragma unroll
      for (int n = 0; n < 4; ++n)
#pragma unroll
        for (int d = 0; d < 16; ++d) outv[n][d] += Ap[n][m] * vf[d];
    }
#pragma unroll
    for (int n = 0; n < 4; ++n) {
      int w0 = pk_fp8(outv[n][0] * 32.f, outv[n][1] * 32.f, outv[n][2] * 32.f, outv[n][3] * 32.f);
      int w1 = pk_fp8(outv[n][4] * 32.f, outv[n][5] * 32.f, outv[n][6] * 32.f, outv[n][7] * 32.f);
      int w2 = pk_fp8(outv[n][8] * 32.f, outv[n][9] * 32.f, outv[n][10] * 32.f, outv[n][11] * 32.f);
      int w3 = pk_fp8(outv[n][12] * 32.f, outv[n][13] * 32.f, outv[n][14] * 32.f, outv[n][15] * 32.f);
      *(int4*)(hmid8 + ((size_t)b * 4 + n) * 1024 + h * 64 + dg * 16) = make_int4(w0, w1, w2, w3);
    }
  }
}

// ---- launch ------------------------------------------------------------------
extern "C" void kernel_launch(void* const* d_in, const int* in_sizes, int n_in,
                              void* d_out, int out_size, void* d_ws, size_t ws_size,
                              hipStream_t stream) {
  (void)in_sizes; (void)n_in; (void)out_size; (void)ws_size;
  const float* x      = (const float*)d_in[0];
  const float* W_qkv  = (const float*)d_in[1];
  const float* W_proj = (const float*)d_in[2];
  const float* b_proj = (const float*)d_in[3];
  const float* W_E    = (const float*)d_in[4];
  const float* W_F    = (const float*)d_in[5];

  float* out0 = (float*)d_out;                     // [B,N,C] fp32
  float* out1 = out0 + (size_t)M_ * C_;            // [B,H,H] fp32

  char* ws = (char*)d_ws;
  // Region 0 (201.3 MB): early = xsel(33.5M) + wqkvT_bf(6.3M); later = qkv_bf.
  unsigned short* xsel   = (unsigned short*)(ws);
  unsigned short* wqkvTb = (unsigned short*)(ws + 33554432);
  unsigned short* qkv_bf = (unsigned short*)(ws);               // overwrites after fixup
  unsigned char*  x8     = (unsigned char*)(ws + 201326592);    // 33.5M; hmid8 aliases it
  unsigned char*  hmid8  = x8;
  unsigned char*  wqkvT8 = (unsigned char*)(ws + 234881024);    // 3.1M
  unsigned char*  wproj8 = (unsigned char*)(ws + 238026752);    // 1.0M
  unsigned short* q1k2   = (unsigned short*)(ws + 239075328);   // 33.5M (end 272.6M)

  cast_x_k<<<32768, 256, 0, stream>>>(x, x8, xsel);
  transpose_wqkv_k<<<dim3(96, 32), dim3(32, 8), 0, stream>>>(W_qkv, wqkvTb, wqkvT8);
  cast_wproj_k<<<1024, 256, 0, stream>>>(W_proj, wproj8);

  // accurate rows for attn_sel: q1 (rows 0..8191), k2 (rows 8192..16383)
  gemm_fixup<<<dim3(8, 128), 256, 0, stream>>>(xsel, wqkvTb, q1k2);

  // GEMM1: qkv = x @ W_qkv (MX-fp8; A scale 1.0, B x32 -> scale 122)
  gemm_mx<0><<<dim3(24, 256), 256, 0, stream>>>(x8, wqkvT8, qkv_bf, nullptr, nullptr,
                                                1024, 3072, 127, 122);

  attn_mfma_k<<<B_ / 4, 256, 0, stream>>>(qkv_bf, q1k2, q1k2 + (size_t)8192 * 1024,
                                          W_E, W_F, hmid8, out1);

  // GEMM2: out = hmid @ W_proj^T + b (both fp8 x32 -> scales 122,122)
  gemm_mx<1><<<dim3(8, 256), 256, 0, stream>>>(hmid8, wproj8, nullptr, out0, b_proj,
                                               1024, 1024, 122, 122);
}

// Round 4
// 556.565 us; speedup vs baseline: 1.2459x; 1.2459x over previous
//
#include <hip/hip_runtime.h>
#include <hip/hip_bf16.h>

// Problem constants
#define B_   8192
#define C_   1024
#define H_   16
#define M_   (B_ * 4)      // 32768 rows
#define K_   1024
#define N1_  3072          // qkv GEMM cols
// SCALE = 0.125 folded into W_qkvT q-section. fp8 weights pre-scaled x32,
// compensated by MX scale byte 122 (=2^-5).

typedef __attribute__((ext_vector_type(8))) short short8;
typedef __attribute__((ext_vector_type(4))) float f32x4;
typedef __attribute__((ext_vector_type(8))) int   int8v;

__device__ __forceinline__ unsigned short f2bf(float f) {
  union { float f; unsigned u; } v; v.f = f;
  unsigned r = v.u + 0x7fffu + ((v.u >> 16) & 1u);   // RNE
  return (unsigned short)(r >> 16);
}
__device__ __forceinline__ float bf2f(unsigned short u) {
  union { unsigned u; float f; } v; v.u = ((unsigned)u) << 16;
  return v.f;
}
__device__ __forceinline__ int pk_fp8(float a, float b, float c, float d) {
  int r = __builtin_amdgcn_cvt_pk_fp8_f32(a, b, 0, false);
  r = __builtin_amdgcn_cvt_pk_fp8_f32(c, d, r, true);
  return r;
}

// ---- cast x: fp8 (scale 1.0) for GEMM1  +  bf16 rows n in {1,2} for fixup ----
__global__ __launch_bounds__(256) void cast_x_k(const float* __restrict__ x,
                                                unsigned char* __restrict__ x8,
                                                unsigned short* __restrict__ xsel) {
  const int row = blockIdx.x;               // 32768 rows (b*4+n)
  const int tid = threadIdx.x;
  float4 v = ((const float4*)(x + (size_t)row * 1024))[tid];
  ((int*)(x8 + (size_t)row * 1024))[tid] = pk_fp8(v.x, v.y, v.z, v.w);
  const int n = row & 3;
  if (n == 1 || n == 2) {                   // wave-uniform branch (per row)
    ushort4 o;
    o.x = f2bf(v.x); o.y = f2bf(v.y); o.z = f2bf(v.z); o.w = f2bf(v.w);
    ((ushort4*)(xsel + ((size_t)(n - 1) * 8192 + (row >> 2)) * 1024))[tid] = o;
  }
}

// ---- transpose W_qkv [1024,3072] -> [3072,1024]: bf16 (fixup B) + fp8 x32 ----
__global__ __launch_bounds__(256) void transpose_wqkv_k(const float* __restrict__ in,
                                                        unsigned short* __restrict__ outb,
                                                        unsigned char* __restrict__ out8) {
  __shared__ float t[32][33];
  int tx = threadIdx.x, ty = threadIdx.y;   // block (32,8)
  int j0 = blockIdx.x * 32, c0 = blockIdx.y * 32;
#pragma unroll
  for (int i = 0; i < 4; ++i)
    t[ty + i * 8][tx] = in[(size_t)(c0 + ty + i * 8) * N1_ + j0 + tx];
  __syncthreads();
#pragma unroll
  for (int i = 0; i < 4; ++i) {
    int j = j0 + ty + i * 8;
    float v = t[tx][ty + i * 8];
    if (j < 1024) v *= 0.125f;              // SCALE folded into q rows
    outb[(size_t)j * K_ + c0 + tx] = f2bf(v);
    out8[(size_t)j * K_ + c0 + tx] =
        (unsigned char)(__builtin_amdgcn_cvt_pk_fp8_f32(v * 32.f, v * 32.f, 0, false) & 0xff);
  }
}

// ---- cast W_proj -> fp8 x32 (no transpose: NT GEMM uses W rows as-is) --------
__global__ __launch_bounds__(256) void cast_wproj_k(const float* __restrict__ in,
                                                    unsigned char* __restrict__ out) {
  int i = blockIdx.x * 256 + threadIdx.x;
  float4 v = ((const float4*)in)[i];
  ((int*)out)[i] = pk_fp8(v.x * 32.f, v.y * 32.f, v.z * 32.f, v.w * 32.f);
}

// ---- bf16 NT GEMM (m97 structure, round-0 verified) for attn_sel fixup ------
// A = xsel [16384,1024]; rows <8192 use Wq section, >=8192 use Wk section.
__global__ __launch_bounds__(256) void gemm_fixup(const unsigned short* __restrict__ A,
                                                  const unsigned short* __restrict__ B0,
                                                  unsigned short* __restrict__ Cbf) {
  __shared__ unsigned short lsA[128 * 32];
  __shared__ unsigned short lsB[128 * 32];
  const int K = 1024, Ncols = 1024;
  const int tid = threadIdx.x;
  const int wave = tid >> 6, lane = tid & 63;
  const int wm = (wave >> 1) * 64, wn = (wave & 1) * 64;
  const long tile_m = (long)blockIdx.y * 128, tile_n = (long)blockIdx.x * 128;
  const unsigned short* Bm = B0 + (tile_m >= 8192 ? (size_t)1024 * 1024 : 0);

  f32x4 acc[4][4] = {};
  const int ci0 = (wave * 2 + 0) * 64 + lane;
  const int ci1 = (wave * 2 + 1) * 64 + lane;
  const int r0 = ci0 >> 2, kc0 = (ci0 & 3) * 8;
  const int r1 = ci1 >> 2, kc1 = (ci1 & 3) * 8;
  const unsigned short* gA0 = A + (tile_m + r0) * K + kc0;
  const unsigned short* gA1 = A + (tile_m + r1) * K + kc1;
  const unsigned short* gB0 = Bm + (tile_n + r0) * K + kc0;
  const unsigned short* gB1 = Bm + (tile_n + r1) * K + kc1;
  unsigned short* dA0 = lsA + (wave * 2 + 0) * 512;
  unsigned short* dA1 = lsA + (wave * 2 + 1) * 512;
  unsigned short* dB0 = lsB + (wave * 2 + 0) * 512;
  unsigned short* dB1 = lsB + (wave * 2 + 1) * 512;
  const int r16 = lane & 15, q8 = (lane >> 4) * 8;

  for (int kt = 0; kt < K; kt += 32) {
    __builtin_amdgcn_global_load_lds((const __attribute__((address_space(1))) void*)(gA0 + kt),
                                     (__attribute__((address_space(3))) void*)dA0, 16, 0, 0);
    __builtin_amdgcn_global_load_lds((const __attribute__((address_space(1))) void*)(gA1 + kt),
                                     (__attribute__((address_space(3))) void*)dA1, 16, 0, 0);
    __builtin_amdgcn_global_load_lds((const __attribute__((address_space(1))) void*)(gB0 + kt),
                                     (__attribute__((address_space(3))) void*)dB0, 16, 0, 0);
    __builtin_amdgcn_global_load_lds((const __attribute__((address_space(1))) void*)(gB1 + kt),
                                     (__attribute__((address_space(3))) void*)dB1, 16, 0, 0);
    __syncthreads();
    short8 afr[4], bfr[4];
#pragma unroll
    for (int mi = 0; mi < 4; ++mi)
      afr[mi] = *(const short8*)&lsA[(wm + mi * 16 + r16) * 32 + q8];
#pragma unroll
    for (int ni = 0; ni < 4; ++ni)
      bfr[ni] = *(const short8*)&lsB[(wn + ni * 16 + r16) * 32 + q8];
#pragma unroll
    for (int mi = 0; mi < 4; ++mi)
#pragma unroll
      for (int ni = 0; ni < 4; ++ni)
        acc[mi][ni] = __builtin_amdgcn_mfma_f32_16x16x32_bf16(afr[mi], bfr[ni], acc[mi][ni], 0, 0, 0);
    __syncthreads();
  }
  const int cl = lane & 15, rq = (lane >> 4) * 4;
#pragma unroll
  for (int mi = 0; mi < 4; ++mi)
#pragma unroll
    for (int ni = 0; ni < 4; ++ni) {
      long col = tile_n + wn + ni * 16 + cl;
#pragma unroll
      for (int r = 0; r < 4; ++r) {
        long row = tile_m + wm + mi * 16 + rq + r;
        Cbf[(size_t)row * Ncols + col] = f2bf(acc[mi][ni][r]);
      }
    }
}

// ---- MX-fp8 NT GEMM, 256x256 tile, 2-phase-per-K-tile pipelined --------------
// C[m,n] = (2^(sA-127))(2^(sB-127)) sum_k A[m,k]B[n,k]
// 512 threads = 8 waves (2M x 4N), BK=128, double-buffered 128 KB LDS.
// Swizzled layout per 128-row block (global-side scatter, linear LDS dest) is
// the round-0/1 verified MX XOR swizzle.
// Schedule (fixes round-1's defects: 9 barriers/tile -> 2, 8 mfma/phase -> 16,
// stage split 4+4 instead of clustered):
//   P0: issue 4 loads(t+1); vmcnt(4) [retire t's 8, keep 4 in flight];
//       s_barrier; ds_read B(8)+A.mi0-3(8); setprio1; 16 mfma; setprio0
//   P1: issue 4 loads(t+1); ds_read A.mi4-7(8); setprio1; 16 mfma; setprio0;
//       s_barrier
// vmcnt never drains to 0 in steady state; compiler inserts fine lgkmcnt for
// the plain-C++ ds_reads (data-dep into mfma).
template <int OUTMODE>  // 0: bf16 C   1: fp32 C + bias
__global__ __launch_bounds__(512) void gemm_mx(const unsigned char* __restrict__ A,
                                               const unsigned char* __restrict__ Bm,
                                               unsigned short* __restrict__ Cbf,
                                               float* __restrict__ Cf,
                                               const float* __restrict__ bias,
                                               int K, int Ncols, int sA, int sB) {
  __shared__ unsigned char lds[131072];

  const int tid = threadIdx.x;
  const int wave = tid >> 6, lane = tid & 63;
  const int wm = (wave >> 2) * 128;        // M-half of the 256-row tile
  const int wn = (wave & 3) * 64;          // N-quarter of the 256-col tile
  const long tile_m = (long)blockIdx.y * 256, tile_n = (long)blockIdx.x * 256;

  f32x4 acc[8][4] = {};

  // staging: per K-tile, 4 A-chunks + 4 B-chunks of 16B per thread.
  unsigned offA[4], offB[4];
#pragma unroll
  for (int j = 0; j < 4; ++j) {
    int ci = j * 512 + tid;                 // 16B-chunk index in [0,2048)
    int blk = ci >> 10, idb = ci & 1023;
    int qg = idb >> 8, id = idb & 255;
    int r2 = (id >> 3) & 1, r3 = (id >> 4) & 1;
    int rr0 = ((id >> 1) & 1) ^ r2, rr1 = ((id >> 2) & 1) ^ r3;
    int row = rr0 | (rr1 << 1) | (r2 << 2) | (r3 << 3) | ((id >> 5) << 4);
    int half = (id & 1) ^ rr0;
    offA[j] = (unsigned)((tile_m + blk * 128 + row) * K + qg * 32 + half * 16);
    offB[j] = (unsigned)((tile_n + blk * 128 + row) * K + qg * 32 + half * 16);
  }

  const int hl = lane & 15, qg = lane >> 4;
  const int swz = (hl & 12) << 3;
  const int laneFragBase = qg * 4096 + ((hl * 32) ^ swz) + ((hl & 1) << 4);
  const int Abase = (wm >> 7) * 16384 + laneFragBase;                 // wm&127==0
  const int Bbase = (wn >> 7) * 16384 + (wn & 64) * 32 + laneFragBase;

  // one 16B A-chunk + one 16B B-chunk for slot j of K-tile at byte offset kt
  auto stage_pair = [&](int kt, unsigned char* dA, unsigned char* dB, int j) {
    __builtin_amdgcn_global_load_lds(
        (const __attribute__((address_space(1))) void*)(A + offA[j] + kt),
        (__attribute__((address_space(3))) void*)(dA + j * 8192 + wave * 1024), 16, 0, 0);
    __builtin_amdgcn_global_load_lds(
        (const __attribute__((address_space(1))) void*)(Bm + offB[j] + kt),
        (__attribute__((address_space(3))) void*)(dB + j * 8192 + wave * 1024), 16, 0, 0);
  };

  const int NT = K >> 7;
  // prologue: tile 0's 8 loads
  stage_pair(0, lds, lds + 32768, 0);
  stage_pair(0, lds, lds + 32768, 1);
  stage_pair(0, lds, lds + 32768, 2);
  stage_pair(0, lds, lds + 32768, 3);

  for (int t = 0; t < NT; ++t) {
    unsigned char* bA = lds + (t & 1) * 65536;
    unsigned char* bB = bA + 32768;
    unsigned char* nA = lds + ((t + 1) & 1) * 65536;
    unsigned char* nB = nA + 32768;
    const int ktn = (t + 1) << 7;

    // ---- P0 ----
    if (t + 1 < NT) {
      stage_pair(ktn, nA, nB, 0);
      stage_pair(ktn, nA, nB, 1);
      asm volatile("s_waitcnt vmcnt(4)" ::: "memory");  // tile t landed; 4 in flight
    } else {
      asm volatile("s_waitcnt vmcnt(0)" ::: "memory");
    }
    __builtin_amdgcn_s_barrier();

    int8v bfr[4];
#pragma unroll
    for (int ni = 0; ni < 4; ++ni) {
      int ad = Bbase + ni * 512;
      int4 h0 = *(const int4*)(bB + ad);
      int4 h1 = *(const int4*)(bB + (ad ^ 16));
      bfr[ni] = int8v{h0.x, h0.y, h0.z, h0.w, h1.x, h1.y, h1.z, h1.w};
    }
    {
      int8v af[4];
#pragma unroll
      for (int mi = 0; mi < 4; ++mi) {
        int ad = Abase + mi * 512;
        int4 h0 = *(const int4*)(bA + ad);
        int4 h1 = *(const int4*)(bA + (ad ^ 16));
        af[mi] = int8v{h0.x, h0.y, h0.z, h0.w, h1.x, h1.y, h1.z, h1.w};
      }
      __builtin_amdgcn_s_setprio(1);
#pragma unroll
      for (int mi = 0; mi < 4; ++mi)
#pragma unroll
        for (int ni = 0; ni < 4; ++ni)
          acc[mi][ni] = __builtin_amdgcn_mfma_scale_f32_16x16x128_f8f6f4(
              af[mi], bfr[ni], acc[mi][ni], 0, 0, 0, sA, 0, sB);
      __builtin_amdgcn_s_setprio(0);
    }

    // ---- P1 ----
    if (t + 1 < NT) {
      stage_pair(ktn, nA, nB, 2);
      stage_pair(ktn, nA, nB, 3);
    }
    {
      int8v af[4];
#pragma unroll
      for (int mi = 0; mi < 4; ++mi) {
        int ad = Abase + (mi + 4) * 512;
        int4 h0 = *(const int4*)(bA + ad);
        int4 h1 = *(const int4*)(bA + (ad ^ 16));
        af[mi] = int8v{h0.x, h0.y, h0.z, h0.w, h1.x, h1.y, h1.z, h1.w};
      }
      __builtin_amdgcn_s_setprio(1);
#pragma unroll
      for (int mi = 0; mi < 4; ++mi)
#pragma unroll
        for (int ni = 0; ni < 4; ++ni)
          acc[mi + 4][ni] = __builtin_amdgcn_mfma_scale_f32_16x16x128_f8f6f4(
              af[mi], bfr[ni], acc[mi + 4][ni], 0, 0, 0, sA, 0, sB);
      __builtin_amdgcn_s_setprio(0);
    }
    __builtin_amdgcn_s_barrier();   // tile exit: protects buffer reuse
  }

  const int cl = lane & 15, rq = (lane >> 4) * 4;
#pragma unroll
  for (int mi = 0; mi < 8; ++mi)
#pragma unroll
    for (int ni = 0; ni < 4; ++ni) {
      long col = tile_n + wn + ni * 16 + cl;
      float bv = (OUTMODE == 1) ? bias[col] : 0.f;
#pragma unroll
      for (int r = 0; r < 4; ++r) {
        long row = tile_m + wm + mi * 16 + rq + r;
        if (OUTMODE == 0)
          Cbf[(size_t)row * Ncols + col] = f2bf(acc[mi][ni][r]);
        else
          Cf[(size_t)row * Ncols + col] = acc[mi][ni][r] + bv;
      }
    }
}

// ---- MFMA attention: 1 wave = 1 batch; attn_sel from accurate bf16 q1/k2 -----
__global__ __launch_bounds__(256) void attn_mfma_k(const unsigned short* __restrict__ qkv,
                                                   const unsigned short* __restrict__ q1,
                                                   const unsigned short* __restrict__ k2,
                                                   const float* __restrict__ WE,
                                                   const float* __restrict__ WF,
                                                   unsigned char* __restrict__ hmid8,
                                                   float* __restrict__ attn_sel) {
  __shared__ float As[4][16 * 17 + 2];
  const int tid = threadIdx.x;
  const int wave = tid >> 6, lane = tid & 63;
  const int b = blockIdx.x * 4 + wave;
  const size_t qb = (size_t)b * 4 * N1_;
  const int hl = lane & 15, qg = lane >> 4;

  // S[n][m] products (fp8-derived qkv: fine, softmax path is insensitive)
  f32x4 accS[4][4] = {};
  f32x4 accSel = {};
#pragma unroll
  for (int ch = 0; ch < 2; ++ch) {
    const int off = ch * 32 + qg * 8;
    short8 qf[4], kf[4];
#pragma unroll
    for (int n = 0; n < 4; ++n)
      qf[n] = *(const short8*)(qkv + qb + (size_t)n * N1_ + 0 + hl * 64 + off);
#pragma unroll
    for (int m = 0; m < 4; ++m)
      kf[m] = *(const short8*)(qkv + qb + (size_t)m * N1_ + 1024 + hl * 64 + off);
#pragma unroll
    for (int n = 0; n < 4; ++n)
#pragma unroll
      for (int m = 0; m < 4; ++m)
        accS[n][m] = __builtin_amdgcn_mfma_f32_16x16x32_bf16(qf[n], kf[m], accS[n][m], 0, 0, 0);
    // accurate attn_sel from bf16 fixup rows
    short8 qs = *(const short8*)(q1 + (size_t)b * 1024 + hl * 64 + off);
    short8 ks = *(const short8*)(k2 + (size_t)b * 1024 + hl * 64 + off);
    accSel = __builtin_amdgcn_mfma_f32_16x16x32_bf16(qs, ks, accSel, 0, 0, 0);
  }

#pragma unroll
  for (int r = 0; r < 4; ++r)
    attn_sel[(size_t)b * 256 + (qg * 4 + r) * 16 + hl] = 1.f / (1.f + __expf(-accSel[r]));

  if ((hl >> 2) == qg) {   // diagonal lanes: per-head softmax + A' = attn.WF
    const int h = hl, rr = h & 3;
    float Sm[4][4];
#pragma unroll
    for (int n = 0; n < 4; ++n)
#pragma unroll
      for (int m = 0; m < 4; ++m) Sm[n][m] = accS[n][m][rr];
#pragma unroll
    for (int n = 0; n < 4; ++n) {
      float lg[4];
#pragma unroll
      for (int p = 0; p < 4; ++p)
        lg[p] = Sm[n][0] * WE[p * 4] + Sm[n][1] * WE[p * 4 + 1] +
                Sm[n][2] * WE[p * 4 + 2] + Sm[n][3] * WE[p * 4 + 3];
      float mx = fmaxf(fmaxf(lg[0], lg[1]), fmaxf(lg[2], lg[3]));
      float e0 = __expf(lg[0] - mx), e1 = __expf(lg[1] - mx);
      float e2 = __expf(lg[2] - mx), e3 = __expf(lg[3] - mx);
      float inv = 1.f / (e0 + e1 + e2 + e3);
      e0 *= inv; e1 *= inv; e2 *= inv; e3 *= inv;
#pragma unroll
      for (int m = 0; m < 4; ++m)
        As[wave][h * 17 + n * 4 + m] =
            e0 * WF[0 * 4 + m] + e1 * WF[1 * 4 + m] + e2 * WF[2 * 4 + m] + e3 * WF[3 * 4 + m];
    }
  }
  __syncthreads();

  {  // out[h,n,d] = sum_m A'[n,m] v[h,m,d]; write hmid as fp8 x32 (scale 122)
    const int h = lane & 15, dg = lane >> 4;
    float Ap[4][4];
#pragma unroll
    for (int n = 0; n < 4; ++n)
#pragma unroll
      for (int m = 0; m < 4; ++m) Ap[n][m] = As[wave][h * 17 + n * 4 + m];

    float outv[4][16] = {};
#pragma unroll
    for (int m = 0; m < 4; ++m) {
      const unsigned short* vp = qkv + qb + (size_t)m * N1_ + 2048 + h * 64 + dg * 16;
      short8 v0 = *(const short8*)(vp);
      short8 v1 = *(const short8*)(vp + 8);
      float vf[16];
#pragma unroll
      for (int j = 0; j < 8; ++j) {
        vf[j] = bf2f((unsigned short)v0[j]);
        vf[8 + j] = bf2f((unsigned short)v1[j]);
      }
#pragma unroll
      for (int n = 0; n < 4; ++n)
#pragma unroll
        for (int d = 0; d < 16; ++d) outv[n][d] += Ap[n][m] * vf[d];
    }
#pragma unroll
    for (int n = 0; n < 4; ++n) {
      int w0 = pk_fp8(outv[n][0] * 32.f, outv[n][1] * 32.f, outv[n][2] * 32.f, outv[n][3] * 32.f);
      int w1 = pk_fp8(outv[n][4] * 32.f, outv[n][5] * 32.f, outv[n][6] * 32.f, outv[n][7] * 32.f);
      int w2 = pk_fp8(outv[n][8] * 32.f, outv[n][9] * 32.f, outv[n][10] * 32.f, outv[n][11] * 32.f);
      int w3 = pk_fp8(outv[n][12] * 32.f, outv[n][13] * 32.f, outv[n][14] * 32.f, outv[n][15] * 32.f);
      *(int4*)(hmid8 + ((size_t)b * 4 + n) * 1024 + h * 64 + dg * 16) = make_int4(w0, w1, w2, w3);
    }
  }
}

// ---- launch ------------------------------------------------------------------
extern "C" void kernel_launch(void* const* d_in, const int* in_sizes, int n_in,
                              void* d_out, int out_size, void* d_ws, size_t ws_size,
                              hipStream_t stream) {
  (void)in_sizes; (void)n_in; (void)out_size; (void)ws_size;
  const float* x      = (const float*)d_in[0];
  const float* W_qkv  = (const float*)d_in[1];
  const float* W_proj = (const float*)d_in[2];
  const float* b_proj = (const float*)d_in[3];
  const float* W_E    = (const float*)d_in[4];
  const float* W_F    = (const float*)d_in[5];

  float* out0 = (float*)d_out;                     // [B,N,C] fp32
  float* out1 = out0 + (size_t)M_ * C_;            // [B,H,H] fp32

  char* ws = (char*)d_ws;
  // Region 0 (201.3 MB): early = xsel(33.5M) + wqkvT_bf(6.3M); later = qkv_bf.
  unsigned short* xsel   = (unsigned short*)(ws);
  unsigned short* wqkvTb = (unsigned short*)(ws + 33554432);
  unsigned short* qkv_bf = (unsigned short*)(ws);               // overwrites after fixup
  unsigned char*  x8     = (unsigned char*)(ws + 201326592);    // 33.5M; hmid8 aliases it
  unsigned char*  hmid8  = x8;
  unsigned char*  wqkvT8 = (unsigned char*)(ws + 234881024);    // 3.1M
  unsigned char*  wproj8 = (unsigned char*)(ws + 238026752);    // 1.0M
  unsigned short* q1k2   = (unsigned short*)(ws + 239075328);   // 33.5M (end 272.6M)

  cast_x_k<<<32768, 256, 0, stream>>>(x, x8, xsel);
  transpose_wqkv_k<<<dim3(96, 32), dim3(32, 8), 0, stream>>>(W_qkv, wqkvTb, wqkvT8);
  cast_wproj_k<<<1024, 256, 0, stream>>>(W_proj, wproj8);

  // accurate rows for attn_sel: q1 (rows 0..8191), k2 (rows 8192..16383)
  gemm_fixup<<<dim3(8, 128), 256, 0, stream>>>(xsel, wqkvTb, q1k2);

  // GEMM1: qkv = x @ W_qkv (MX-fp8; A scale 1.0, B x32 -> scale 122)
  gemm_mx<0><<<dim3(12, 128), 512, 0, stream>>>(x8, wqkvT8, qkv_bf, nullptr, nullptr,
                                                1024, 3072, 127, 122);

  attn_mfma_k<<<B_ / 4, 256, 0, stream>>>(qkv_bf, q1k2, q1k2 + (size_t)8192 * 1024,
                                          W_E, W_F, hmid8, out1);

  // GEMM2: out = hmid @ W_proj^T + b (both fp8 x32 -> scales 122,122)
  gemm_mx<1><<<dim3(4, 128), 512, 0, stream>>>(hmid8, wproj8, nullptr, out0, b_proj,
                                               1024, 1024, 122, 122);
}

// Round 5
// 554.855 us; speedup vs baseline: 1.2498x; 1.0031x over previous
//
#include <hip/hip_runtime.h>
#include <hip/hip_bf16.h>

// Problem constants
#define B_   8192
#define C_   1024
#define H_   16
#define M_   (B_ * 4)      // 32768 rows
#define K_   1024
#define N1_  3072          // qkv GEMM cols
// SCALE = 0.125 folded into W_qkvT q-section. fp8 weights pre-scaled x32,
// compensated by MX scale byte 122 (=2^-5).

typedef __attribute__((ext_vector_type(8))) short short8;
typedef __attribute__((ext_vector_type(4))) float f32x4;
typedef __attribute__((ext_vector_type(8))) int   int8v;

__device__ __forceinline__ unsigned short f2bf(float f) {
  union { float f; unsigned u; } v; v.f = f;
  unsigned r = v.u + 0x7fffu + ((v.u >> 16) & 1u);   // RNE
  return (unsigned short)(r >> 16);
}
__device__ __forceinline__ float bf2f(unsigned short u) {
  union { unsigned u; float f; } v; v.u = ((unsigned)u) << 16;
  return v.f;
}
__device__ __forceinline__ int pk_fp8(float a, float b, float c, float d) {
  int r = __builtin_amdgcn_cvt_pk_fp8_f32(a, b, 0, false);
  r = __builtin_amdgcn_cvt_pk_fp8_f32(c, d, r, true);
  return r;
}

// Fragment-packed B layout (producer side). For B row j, K-col c (bytes):
//   po = (j>>4)*16384 + (c>>7)*2048 + ((c>>4)&1)*1024 + ((c>>5)&3)*256
//        + (j&15)*16 + (c&15)
// so that a wave's MFMA B-fragment load for (ni, half h) is ONE coalesced
// dwordx4 at  base + (row_grp+ni)*16384 + kt*16 + h*1024 + lane*16.
__device__ __forceinline__ size_t bpack(int j, int c) {
  return (size_t)(j >> 4) * 16384 + (size_t)(c >> 7) * 2048 +
         (size_t)((c >> 4) & 1) * 1024 + (size_t)((c >> 5) & 3) * 256 +
         (size_t)(j & 15) * 16 + (size_t)(c & 15);
}

// ---- cast x: fp8 (scale 1.0) for GEMM1  +  bf16 rows n in {1,2} for fixup ----
__global__ __launch_bounds__(256) void cast_x_k(const float* __restrict__ x,
                                                unsigned char* __restrict__ x8,
                                                unsigned short* __restrict__ xsel) {
  const int row = blockIdx.x;               // 32768 rows (b*4+n)
  const int tid = threadIdx.x;
  float4 v = ((const float4*)(x + (size_t)row * 1024))[tid];
  ((int*)(x8 + (size_t)row * 1024))[tid] = pk_fp8(v.x, v.y, v.z, v.w);
  const int n = row & 3;
  if (n == 1 || n == 2) {                   // wave-uniform branch (per row)
    ushort4 o;
    o.x = f2bf(v.x); o.y = f2bf(v.y); o.z = f2bf(v.z); o.w = f2bf(v.w);
    ((ushort4*)(xsel + ((size_t)(n - 1) * 8192 + (row >> 2)) * 1024))[tid] = o;
  }
}

// ---- transpose W_qkv [1024,3072] -> [3072,1024]: bf16 (fixup B, row-major)
//      + fp8 x32 in fragment-packed layout for gemm_mx ------------------------
__global__ __launch_bounds__(256) void transpose_wqkv_k(const float* __restrict__ in,
                                                        unsigned short* __restrict__ outb,
                                                        unsigned char* __restrict__ out8) {
  __shared__ float t[32][33];
  int tx = threadIdx.x, ty = threadIdx.y;   // block (32,8)
  int j0 = blockIdx.x * 32, c0 = blockIdx.y * 32;
#pragma unroll
  for (int i = 0; i < 4; ++i)
    t[ty + i * 8][tx] = in[(size_t)(c0 + ty + i * 8) * N1_ + j0 + tx];
  __syncthreads();
#pragma unroll
  for (int i = 0; i < 4; ++i) {
    int j = j0 + ty + i * 8;
    int c = c0 + tx;
    float v = t[tx][ty + i * 8];
    if (j < 1024) v *= 0.125f;              // SCALE folded into q rows
    outb[(size_t)j * K_ + c] = f2bf(v);
    out8[bpack(j, c)] =
        (unsigned char)(__builtin_amdgcn_cvt_pk_fp8_f32(v * 32.f, v * 32.f, 0, false) & 0xff);
  }
}

// ---- cast W_proj -> fp8 x32, fragment-packed (NT GEMM uses W rows as-is) -----
__global__ __launch_bounds__(256) void cast_wproj_k(const float* __restrict__ in,
                                                    unsigned char* __restrict__ out) {
  int i = blockIdx.x * 256 + threadIdx.x;
  float4 v = ((const float4*)in)[i];
  int f = i * 4;                            // flat element index
  int j = f >> 10, c = f & 1023;            // row, col (c % 4 == 0)
  *(int*)(out + bpack(j, c)) = pk_fp8(v.x * 32.f, v.y * 32.f, v.z * 32.f, v.w * 32.f);
}

// ---- bf16 NT GEMM (m97 structure, round-0 verified) for attn_sel fixup ------
// A = xsel [16384,1024]; rows <8192 use Wq section, >=8192 use Wk section.
__global__ __launch_bounds__(256) void gemm_fixup(const unsigned short* __restrict__ A,
                                                  const unsigned short* __restrict__ B0,
                                                  unsigned short* __restrict__ Cbf) {
  __shared__ unsigned short lsA[128 * 32];
  __shared__ unsigned short lsB[128 * 32];
  const int K = 1024, Ncols = 1024;
  const int tid = threadIdx.x;
  const int wave = tid >> 6, lane = tid & 63;
  const int wm = (wave >> 1) * 64, wn = (wave & 1) * 64;
  const long tile_m = (long)blockIdx.y * 128, tile_n = (long)blockIdx.x * 128;
  const unsigned short* Bm = B0 + (tile_m >= 8192 ? (size_t)1024 * 1024 : 0);

  f32x4 acc[4][4] = {};
  const int ci0 = (wave * 2 + 0) * 64 + lane;
  const int ci1 = (wave * 2 + 1) * 64 + lane;
  const int r0 = ci0 >> 2, kc0 = (ci0 & 3) * 8;
  const int r1 = ci1 >> 2, kc1 = (ci1 & 3) * 8;
  const unsigned short* gA0 = A + (tile_m + r0) * K + kc0;
  const unsigned short* gA1 = A + (tile_m + r1) * K + kc1;
  const unsigned short* gB0 = Bm + (tile_n + r0) * K + kc0;
  const unsigned short* gB1 = Bm + (tile_n + r1) * K + kc1;
  unsigned short* dA0 = lsA + (wave * 2 + 0) * 512;
  unsigned short* dA1 = lsA + (wave * 2 + 1) * 512;
  unsigned short* dB0 = lsB + (wave * 2 + 0) * 512;
  unsigned short* dB1 = lsB + (wave * 2 + 1) * 512;
  const int r16 = lane & 15, q8 = (lane >> 4) * 8;

  for (int kt = 0; kt < K; kt += 32) {
    __builtin_amdgcn_global_load_lds((const __attribute__((address_space(1))) void*)(gA0 + kt),
                                     (__attribute__((address_space(3))) void*)dA0, 16, 0, 0);
    __builtin_amdgcn_global_load_lds((const __attribute__((address_space(1))) void*)(gA1 + kt),
                                     (__attribute__((address_space(3))) void*)dA1, 16, 0, 0);
    __builtin_amdgcn_global_load_lds((const __attribute__((address_space(1))) void*)(gB0 + kt),
                                     (__attribute__((address_space(3))) void*)dB0, 16, 0, 0);
    __builtin_amdgcn_global_load_lds((const __attribute__((address_space(1))) void*)(gB1 + kt),
                                     (__attribute__((address_space(3))) void*)dB1, 16, 0, 0);
    __syncthreads();
    short8 afr[4], bfr[4];
#pragma unroll
    for (int mi = 0; mi < 4; ++mi)
      afr[mi] = *(const short8*)&lsA[(wm + mi * 16 + r16) * 32 + q8];
#pragma unroll
    for (int ni = 0; ni < 4; ++ni)
      bfr[ni] = *(const short8*)&lsB[(wn + ni * 16 + r16) * 32 + q8];
#pragma unroll
    for (int mi = 0; mi < 4; ++mi)
#pragma unroll
      for (int ni = 0; ni < 4; ++ni)
        acc[mi][ni] = __builtin_amdgcn_mfma_f32_16x16x32_bf16(afr[mi], bfr[ni], acc[mi][ni], 0, 0, 0);
    __syncthreads();
  }
  const int cl = lane & 15, rq = (lane >> 4) * 4;
#pragma unroll
  for (int mi = 0; mi < 4; ++mi)
#pragma unroll
    for (int ni = 0; ni < 4; ++ni) {
      long col = tile_n + wn + ni * 16 + cl;
#pragma unroll
      for (int r = 0; r < 4; ++r) {
        long row = tile_m + wm + mi * 16 + rq + r;
        Cbf[(size_t)row * Ncols + col] = f2bf(acc[mi][ni][r]);
      }
    }
}

// ---- MX-fp8 NT GEMM, 256x256 tile, A-only LDS + direct packed-B --------------
// C[m,n] = (2^(sA-127))(2^(sB-127)) sum_k A[m,k]B[n,k]
// 512 threads = 8 waves (2M x 4N), BK=128.
// A: staged via global_load_lds with the verified MX XOR swizzle into a
//    2 x 32KB double buffer (64KB LDS total).
// B: fragment-packed in memory (see bpack); each wave loads its B-fragments
//    DIRECTLY global->reg with fully-coalesced dwordx4 (base + lane*16).
//    B panel is L2-resident; loads issue at tile top, compiler inserts the
//    counted vmcnt before first MFMA use (~400cy lead).
// Schedule per K-tile (ONE barrier, ONE manual vmcnt):
//   vmcnt(0) [A-stage(t) landed; full-tile lead] ; s_barrier [buf protect]
//   load B(t) frags (8 dwordx4) ; issue A-stage(t+1) (8 global_load_lds)
//   ds_read A0 (8) ; 16 mfma ; ds_read A1 (8) ; 16 mfma
// LDS-pipe work/tile ~halved vs round-4 (B reads+writes removed) -> MFMA-pipe
// becomes the long pole.
template <int OUTMODE>  // 0: bf16 C   1: fp32 C + bias
__global__ __launch_bounds__(512) void gemm_mx(const unsigned char* __restrict__ A,
                                               const unsigned char* __restrict__ Bm,
                                               unsigned short* __restrict__ Cbf,
                                               float* __restrict__ Cf,
                                               const float* __restrict__ bias,
                                               int K, int Ncols, int sA, int sB) {
  __shared__ unsigned char lds[65536];     // 2 x 32KB A double buffer

  const int tid = threadIdx.x;
  const int wave = tid >> 6, lane = tid & 63;
  const int wm = (wave >> 2) * 128;        // M-half of the 256-row tile
  const int wn = (wave & 3) * 64;          // N-quarter of the 256-col tile
  const long tile_m = (long)blockIdx.y * 256, tile_n = (long)blockIdx.x * 256;

  f32x4 acc[8][4] = {};

  // A staging: per K-tile, 4 chunks of 16B per thread (swizzle on global side)
  unsigned offA[4];
#pragma unroll
  for (int j = 0; j < 4; ++j) {
    int ci = j * 512 + tid;                 // 16B-chunk index in [0,2048)
    int blk = ci >> 10, idb = ci & 1023;
    int qgs = idb >> 8, id = idb & 255;
    int r2 = (id >> 3) & 1, r3 = (id >> 4) & 1;
    int rr0 = ((id >> 1) & 1) ^ r2, rr1 = ((id >> 2) & 1) ^ r3;
    int row = rr0 | (rr1 << 1) | (r2 << 2) | (r3 << 3) | ((id >> 5) << 4);
    int half = (id & 1) ^ rr0;
    offA[j] = (unsigned)((tile_m + blk * 128 + row) * K + qgs * 32 + half * 16);
  }

  const int hl = lane & 15, qg = lane >> 4;
  const int swz = (hl & 12) << 3;
  const int laneFragBase = qg * 4096 + ((hl * 32) ^ swz) + ((hl & 1) << 4);
  const int Abase = (wm >> 7) * 16384 + laneFragBase;                 // wm&127==0

  // packed-B: wave's quarter starts at row-group (tile_n+wn)>>4; lane-coalesced
  const unsigned char* gB = Bm + (size_t)((tile_n + wn) >> 4) * 16384 + (size_t)lane * 16;

  auto stageA = [&](int kt, unsigned char* dA) {
#pragma unroll
    for (int j = 0; j < 4; ++j)
      __builtin_amdgcn_global_load_lds(
          (const __attribute__((address_space(1))) void*)(A + offA[j] + kt),
          (__attribute__((address_space(3))) void*)(dA + j * 8192 + wave * 1024), 16, 0, 0);
  };

  const int NT = K >> 7;
  stageA(0, lds);                           // prologue: tile 0's A

  for (int t = 0; t < NT; ++t) {
    unsigned char* bA = lds + (t & 1) * 32768;

    asm volatile("s_waitcnt vmcnt(0)" ::: "memory");  // A-stage(t) landed
    __builtin_amdgcn_s_barrier();                     // all waves left buf[(t-1)&1]

    // B(t) fragments: 8 coalesced dwordx4 (compiler inserts counted waits)
    const int kt16 = t * 2048;              // (kt>>7)*2048
    int8v bfr[4];
#pragma unroll
    for (int ni = 0; ni < 4; ++ni) {
      const unsigned char* bp = gB + (size_t)ni * 16384 + kt16;
      int4 h0 = *(const int4*)bp;           // half 0
      int4 h1 = *(const int4*)(bp + 1024);  // half 1
      bfr[ni] = int8v{h0.x, h0.y, h0.z, h0.w, h1.x, h1.y, h1.z, h1.w};
    }

    if (t + 1 < NT)                         // prefetch next A (full-tile lead)
      stageA((t + 1) << 7, lds + ((t + 1) & 1) * 32768);

    {  // phase 0: A rows wm..wm+63
      int8v af[4];
#pragma unroll
      for (int mi = 0; mi < 4; ++mi) {
        int ad = Abase + mi * 512;
        int4 h0 = *(const int4*)(bA + ad);
        int4 h1 = *(const int4*)(bA + (ad ^ 16));
        af[mi] = int8v{h0.x, h0.y, h0.z, h0.w, h1.x, h1.y, h1.z, h1.w};
      }
      __builtin_amdgcn_s_setprio(1);
#pragma unroll
      for (int mi = 0; mi < 4; ++mi)
#pragma unroll
        for (int ni = 0; ni < 4; ++ni)
          acc[mi][ni] = __builtin_amdgcn_mfma_scale_f32_16x16x128_f8f6f4(
              af[mi], bfr[ni], acc[mi][ni], 0, 0, 0, sA, 0, sB);
      __builtin_amdgcn_s_setprio(0);
    }
    {  // phase 1: A rows wm+64..wm+127
      int8v af[4];
#pragma unroll
      for (int mi = 0; mi < 4; ++mi) {
        int ad = Abase + (mi + 4) * 512;
        int4 h0 = *(const int4*)(bA + ad);
        int4 h1 = *(const int4*)(bA + (ad ^ 16));
        af[mi] = int8v{h0.x, h0.y, h0.z, h0.w, h1.x, h1.y, h1.z, h1.w};
      }
      __builtin_amdgcn_s_setprio(1);
#pragma unroll
      for (int mi = 0; mi < 4; ++mi)
#pragma unroll
        for (int ni = 0; ni < 4; ++ni)
          acc[mi + 4][ni] = __builtin_amdgcn_mfma_scale_f32_16x16x128_f8f6f4(
              af[mi], bfr[ni], acc[mi + 4][ni], 0, 0, 0, sA, 0, sB);
      __builtin_amdgcn_s_setprio(0);
    }
  }

  const int cl = lane & 15, rq = (lane >> 4) * 4;
#pragma unroll
  for (int mi = 0; mi < 8; ++mi)
#pragma unroll
    for (int ni = 0; ni < 4; ++ni) {
      long col = tile_n + wn + ni * 16 + cl;
      float bv = (OUTMODE == 1) ? bias[col] : 0.f;
#pragma unroll
      for (int r = 0; r < 4; ++r) {
        long row = tile_m + wm + mi * 16 + rq + r;
        if (OUTMODE == 0)
          Cbf[(size_t)row * Ncols + col] = f2bf(acc[mi][ni][r]);
        else
          Cf[(size_t)row * Ncols + col] = acc[mi][ni][r] + bv;
      }
    }
}

// ---- MFMA attention: 1 wave = 1 batch; attn_sel from accurate bf16 q1/k2 -----
__global__ __launch_bounds__(256) void attn_mfma_k(const unsigned short* __restrict__ qkv,
                                                   const unsigned short* __restrict__ q1,
                                                   const unsigned short* __restrict__ k2,
                                                   const float* __restrict__ WE,
                                                   const float* __restrict__ WF,
                                                   unsigned char* __restrict__ hmid8,
                                                   float* __restrict__ attn_sel) {
  __shared__ float As[4][16 * 17 + 2];
  const int tid = threadIdx.x;
  const int wave = tid >> 6, lane = tid & 63;
  const int b = blockIdx.x * 4 + wave;
  const size_t qb = (size_t)b * 4 * N1_;
  const int hl = lane & 15, qg = lane >> 4;

  // S[n][m] products (fp8-derived qkv: fine, softmax path is insensitive)
  f32x4 accS[4][4] = {};
  f32x4 accSel = {};
#pragma unroll
  for (int ch = 0; ch < 2; ++ch) {
    const int off = ch * 32 + qg * 8;
    short8 qf[4], kf[4];
#pragma unroll
    for (int n = 0; n < 4; ++n)
      qf[n] = *(const short8*)(qkv + qb + (size_t)n * N1_ + 0 + hl * 64 + off);
#pragma unroll
    for (int m = 0; m < 4; ++m)
      kf[m] = *(const short8*)(qkv + qb + (size_t)m * N1_ + 1024 + hl * 64 + off);
#pragma unroll
    for (int n = 0; n < 4; ++n)
#pragma unroll
      for (int m = 0; m < 4; ++m)
        accS[n][m] = __builtin_amdgcn_mfma_f32_16x16x32_bf16(qf[n], kf[m], accS[n][m], 0, 0, 0);
    // accurate attn_sel from bf16 fixup rows
    short8 qs = *(const short8*)(q1 + (size_t)b * 1024 + hl * 64 + off);
    short8 ks = *(const short8*)(k2 + (size_t)b * 1024 + hl * 64 + off);
    accSel = __builtin_amdgcn_mfma_f32_16x16x32_bf16(qs, ks, accSel, 0, 0, 0);
  }

#pragma unroll
  for (int r = 0; r < 4; ++r)
    attn_sel[(size_t)b * 256 + (qg * 4 + r) * 16 + hl] = 1.f / (1.f + __expf(-accSel[r]));

  if ((hl >> 2) == qg) {   // diagonal lanes: per-head softmax + A' = attn.WF
    const int h = hl, rr = h & 3;
    float Sm[4][4];
#pragma unroll
    for (int n = 0; n < 4; ++n)
#pragma unroll
      for (int m = 0; m < 4; ++m) Sm[n][m] = accS[n][m][rr];
#pragma unroll
    for (int n = 0; n < 4; ++n) {
      float lg[4];
#pragma unroll
      for (int p = 0; p < 4; ++p)
        lg[p] = Sm[n][0] * WE[p * 4] + Sm[n][1] * WE[p * 4 + 1] +
                Sm[n][2] * WE[p * 4 + 2] + Sm[n][3] * WE[p * 4 + 3];
      float mx = fmaxf(fmaxf(lg[0], lg[1]), fmaxf(lg[2], lg[3]));
      float e0 = __expf(lg[0] - mx), e1 = __expf(lg[1] - mx);
      float e2 = __expf(lg[2] - mx), e3 = __expf(lg[3] - mx);
      float inv = 1.f / (e0 + e1 + e2 + e3);
      e0 *= inv; e1 *= inv; e2 *= inv; e3 *= inv;
#pragma unroll
      for (int m = 0; m < 4; ++m)
        As[wave][h * 17 + n * 4 + m] =
            e0 * WF[0 * 4 + m] + e1 * WF[1 * 4 + m] + e2 * WF[2 * 4 + m] + e3 * WF[3 * 4 + m];
    }
  }
  __syncthreads();

  {  // out[h,n,d] = sum_m A'[n,m] v[h,m,d]; write hmid as fp8 x32 (scale 122)
    const int h = lane & 15, dg = lane >> 4;
    float Ap[4][4];
#pragma unroll
    for (int n = 0; n < 4; ++n)
#pragma unroll
      for (int m = 0; m < 4; ++m) Ap[n][m] = As[wave][h * 17 + n * 4 + m];

    float outv[4][16] = {};
#pragma unroll
    for (int m = 0; m < 4; ++m) {
      const unsigned short* vp = qkv + qb + (size_t)m * N1_ + 2048 + h * 64 + dg * 16;
      short8 v0 = *(const short8*)(vp);
      short8 v1 = *(const short8*)(vp + 8);
      float vf[16];
#pragma unroll
      for (int j = 0; j < 8; ++j) {
        vf[j] = bf2f((unsigned short)v0[j]);
        vf[8 + j] = bf2f((unsigned short)v1[j]);
      }
#pragma unroll
      for (int n = 0; n < 4; ++n)
#pragma unroll
        for (int d = 0; d < 16; ++d) outv[n][d] += Ap[n][m] * vf[d];
    }
#pragma unroll
    for (int n = 0; n < 4; ++n) {
      int w0 = pk_fp8(outv[n][0] * 32.f, outv[n][1] * 32.f, outv[n][2] * 32.f, outv[n][3] * 32.f);
      int w1 = pk_fp8(outv[n][4] * 32.f, outv[n][5] * 32.f, outv[n][6] * 32.f, outv[n][7] * 32.f);
      int w2 = pk_fp8(outv[n][8] * 32.f, outv[n][9] * 32.f, outv[n][10] * 32.f, outv[n][11] * 32.f);
      int w3 = pk_fp8(outv[n][12] * 32.f, outv[n][13] * 32.f, outv[n][14] * 32.f, outv[n][15] * 32.f);
      *(int4*)(hmid8 + ((size_t)b * 4 + n) * 1024 + h * 64 + dg * 16) = make_int4(w0, w1, w2, w3);
    }
  }
}

// ---- launch ------------------------------------------------------------------
extern "C" void kernel_launch(void* const* d_in, const int* in_sizes, int n_in,
                              void* d_out, int out_size, void* d_ws, size_t ws_size,
                              hipStream_t stream) {
  (void)in_sizes; (void)n_in; (void)out_size; (void)ws_size;
  const float* x      = (const float*)d_in[0];
  const float* W_qkv  = (const float*)d_in[1];
  const float* W_proj = (const float*)d_in[2];
  const float* b_proj = (const float*)d_in[3];
  const float* W_E    = (const float*)d_in[4];
  const float* W_F    = (const float*)d_in[5];

  float* out0 = (float*)d_out;                     // [B,N,C] fp32
  float* out1 = out0 + (size_t)M_ * C_;            // [B,H,H] fp32

  char* ws = (char*)d_ws;
  // Region 0 (201.3 MB): early = xsel(33.5M) + wqkvT_bf(6.3M); later = qkv_bf.
  unsigned short* xsel   = (unsigned short*)(ws);
  unsigned short* wqkvTb = (unsigned short*)(ws + 33554432);
  unsigned short* qkv_bf = (unsigned short*)(ws);               // overwrites after fixup
  unsigned char*  x8     = (unsigned char*)(ws + 201326592);    // 33.5M; hmid8 aliases it
  unsigned char*  hmid8  = x8;
  unsigned char*  wqkvT8 = (unsigned char*)(ws + 234881024);    // 3.1M (fragment-packed)
  unsigned char*  wproj8 = (unsigned char*)(ws + 238026752);    // 1.0M (fragment-packed)
  unsigned short* q1k2   = (unsigned short*)(ws + 239075328);   // 33.5M (end 272.6M)

  cast_x_k<<<32768, 256, 0, stream>>>(x, x8, xsel);
  transpose_wqkv_k<<<dim3(96, 32), dim3(32, 8), 0, stream>>>(W_qkv, wqkvTb, wqkvT8);
  cast_wproj_k<<<1024, 256, 0, stream>>>(W_proj, wproj8);

  // accurate rows for attn_sel: q1 (rows 0..8191), k2 (rows 8192..16383)
  gemm_fixup<<<dim3(8, 128), 256, 0, stream>>>(xsel, wqkvTb, q1k2);

  // GEMM1: qkv = x @ W_qkv (MX-fp8; A scale 1.0, B x32 -> scale 122)
  gemm_mx<0><<<dim3(12, 128), 512, 0, stream>>>(x8, wqkvT8, qkv_bf, nullptr, nullptr,
                                                1024, 3072, 127, 122);

  attn_mfma_k<<<B_ / 4, 256, 0, stream>>>(qkv_bf, q1k2, q1k2 + (size_t)8192 * 1024,
                                          W_E, W_F, hmid8, out1);

  // GEMM2: out = hmid @ W_proj^T + b (both fp8 x32 -> scales 122,122)
  gemm_mx<1><<<dim3(4, 128), 512, 0, stream>>>(hmid8, wproj8, nullptr, out0, b_proj,
                                               1024, 1024, 122, 122);
}

// Round 6
// 547.047 us; speedup vs baseline: 1.2676x; 1.0143x over previous
//
#include <hip/hip_runtime.h>
#include <hip/hip_bf16.h>

// Problem constants
#define B_   8192
#define C_   1024
#define H_   16
#define M_   (B_ * 4)      // 32768 rows
#define K_   1024
#define N1_  3072          // qkv GEMM cols
// SCALE = 0.125 folded into W_qkvT q-section. fp8 weights pre-scaled x32,
// compensated by MX scale byte 122 (=2^-5).

typedef __attribute__((ext_vector_type(8))) short short8;
typedef __attribute__((ext_vector_type(4))) float f32x4;
typedef __attribute__((ext_vector_type(8))) int   int8v;

__device__ __forceinline__ unsigned short f2bf(float f) {
  union { float f; unsigned u; } v; v.f = f;
  unsigned r = v.u + 0x7fffu + ((v.u >> 16) & 1u);   // RNE
  return (unsigned short)(r >> 16);
}
__device__ __forceinline__ float bf2f(unsigned short u) {
  union { unsigned u; float f; } v; v.u = ((unsigned)u) << 16;
  return v.f;
}
__device__ __forceinline__ int pk_fp8(float a, float b, float c, float d) {
  int r = __builtin_amdgcn_cvt_pk_fp8_f32(a, b, 0, false);
  r = __builtin_amdgcn_cvt_pk_fp8_f32(c, d, r, true);
  return r;
}

// Fragment-packed B layout (producer side). For B row j, K-col c (bytes):
//   po = (j>>4)*16384 + (c>>7)*2048 + ((c>>4)&1)*1024 + ((c>>5)&3)*256
//        + (j&15)*16 + (c&15)
// so that a wave's MFMA B-fragment load for (ni, half h) is ONE coalesced
// dwordx4 at  base + (row_grp+ni)*16384 + kt*16 + h*1024 + lane*16.
__device__ __forceinline__ size_t bpack(int j, int c) {
  return (size_t)(j >> 4) * 16384 + (size_t)(c >> 7) * 2048 +
         (size_t)((c >> 4) & 1) * 1024 + (size_t)((c >> 5) & 3) * 256 +
         (size_t)(j & 15) * 16 + (size_t)(c & 15);
}

// ---- cast x: fp8 (scale 1.0) for GEMM1  +  bf16 rows n in {1,2} for fixup ----
__global__ __launch_bounds__(256) void cast_x_k(const float* __restrict__ x,
                                                unsigned char* __restrict__ x8,
                                                unsigned short* __restrict__ xsel) {
  const int row = blockIdx.x;               // 32768 rows (b*4+n)
  const int tid = threadIdx.x;
  float4 v = ((const float4*)(x + (size_t)row * 1024))[tid];
  ((int*)(x8 + (size_t)row * 1024))[tid] = pk_fp8(v.x, v.y, v.z, v.w);
  const int n = row & 3;
  if (n == 1 || n == 2) {                   // wave-uniform branch (per row)
    ushort4 o;
    o.x = f2bf(v.x); o.y = f2bf(v.y); o.z = f2bf(v.z); o.w = f2bf(v.w);
    ((ushort4*)(xsel + ((size_t)(n - 1) * 8192 + (row >> 2)) * 1024))[tid] = o;
  }
}

// ---- transpose W_qkv [1024,3072] -> [3072,1024]: bf16 (fixup B, row-major)
//      + fp8 x32 in fragment-packed layout for gemm_mx ------------------------
__global__ __launch_bounds__(256) void transpose_wqkv_k(const float* __restrict__ in,
                                                        unsigned short* __restrict__ outb,
                                                        unsigned char* __restrict__ out8) {
  __shared__ float t[32][33];
  int tx = threadIdx.x, ty = threadIdx.y;   // block (32,8)
  int j0 = blockIdx.x * 32, c0 = blockIdx.y * 32;
#pragma unroll
  for (int i = 0; i < 4; ++i)
    t[ty + i * 8][tx] = in[(size_t)(c0 + ty + i * 8) * N1_ + j0 + tx];
  __syncthreads();
#pragma unroll
  for (int i = 0; i < 4; ++i) {
    int j = j0 + ty + i * 8;
    int c = c0 + tx;
    float v = t[tx][ty + i * 8];
    if (j < 1024) v *= 0.125f;              // SCALE folded into q rows
    outb[(size_t)j * K_ + c] = f2bf(v);
    out8[bpack(j, c)] =
        (unsigned char)(__builtin_amdgcn_cvt_pk_fp8_f32(v * 32.f, v * 32.f, 0, false) & 0xff);
  }
}

// ---- cast W_proj -> fp8 x32, fragment-packed (NT GEMM uses W rows as-is) -----
__global__ __launch_bounds__(256) void cast_wproj_k(const float* __restrict__ in,
                                                    unsigned char* __restrict__ out) {
  int i = blockIdx.x * 256 + threadIdx.x;
  float4 v = ((const float4*)in)[i];
  int f = i * 4;                            // flat element index
  int j = f >> 10, c = f & 1023;            // row, col (c % 4 == 0)
  *(int*)(out + bpack(j, c)) = pk_fp8(v.x * 32.f, v.y * 32.f, v.z * 32.f, v.w * 32.f);
}

// ---- bf16 NT GEMM (m97 structure, round-0 verified) for attn_sel fixup ------
// A = xsel [16384,1024]; rows <8192 use Wq section, >=8192 use Wk section.
__global__ __launch_bounds__(256) void gemm_fixup(const unsigned short* __restrict__ A,
                                                  const unsigned short* __restrict__ B0,
                                                  unsigned short* __restrict__ Cbf) {
  __shared__ unsigned short lsA[128 * 32];
  __shared__ unsigned short lsB[128 * 32];
  const int K = 1024, Ncols = 1024;
  const int tid = threadIdx.x;
  const int wave = tid >> 6, lane = tid & 63;
  const int wm = (wave >> 1) * 64, wn = (wave & 1) * 64;
  const long tile_m = (long)blockIdx.y * 128, tile_n = (long)blockIdx.x * 128;
  const unsigned short* Bm = B0 + (tile_m >= 8192 ? (size_t)1024 * 1024 : 0);

  f32x4 acc[4][4] = {};
  const int ci0 = (wave * 2 + 0) * 64 + lane;
  const int ci1 = (wave * 2 + 1) * 64 + lane;
  const int r0 = ci0 >> 2, kc0 = (ci0 & 3) * 8;
  const int r1 = ci1 >> 2, kc1 = (ci1 & 3) * 8;
  const unsigned short* gA0 = A + (tile_m + r0) * K + kc0;
  const unsigned short* gA1 = A + (tile_m + r1) * K + kc1;
  const unsigned short* gB0 = Bm + (tile_n + r0) * K + kc0;
  const unsigned short* gB1 = Bm + (tile_n + r1) * K + kc1;
  unsigned short* dA0 = lsA + (wave * 2 + 0) * 512;
  unsigned short* dA1 = lsA + (wave * 2 + 1) * 512;
  unsigned short* dB0 = lsB + (wave * 2 + 0) * 512;
  unsigned short* dB1 = lsB + (wave * 2 + 1) * 512;
  const int r16 = lane & 15, q8 = (lane >> 4) * 8;

  for (int kt = 0; kt < K; kt += 32) {
    __builtin_amdgcn_global_load_lds((const __attribute__((address_space(1))) void*)(gA0 + kt),
                                     (__attribute__((address_space(3))) void*)dA0, 16, 0, 0);
    __builtin_amdgcn_global_load_lds((const __attribute__((address_space(1))) void*)(gA1 + kt),
                                     (__attribute__((address_space(3))) void*)dA1, 16, 0, 0);
    __builtin_amdgcn_global_load_lds((const __attribute__((address_space(1))) void*)(gB0 + kt),
                                     (__attribute__((address_space(3))) void*)dB0, 16, 0, 0);
    __builtin_amdgcn_global_load_lds((const __attribute__((address_space(1))) void*)(gB1 + kt),
                                     (__attribute__((address_space(3))) void*)dB1, 16, 0, 0);
    __syncthreads();
    short8 afr[4], bfr[4];
#pragma unroll
    for (int mi = 0; mi < 4; ++mi)
      afr[mi] = *(const short8*)&lsA[(wm + mi * 16 + r16) * 32 + q8];
#pragma unroll
    for (int ni = 0; ni < 4; ++ni)
      bfr[ni] = *(const short8*)&lsB[(wn + ni * 16 + r16) * 32 + q8];
#pragma unroll
    for (int mi = 0; mi < 4; ++mi)
#pragma unroll
      for (int ni = 0; ni < 4; ++ni)
        acc[mi][ni] = __builtin_amdgcn_mfma_f32_16x16x32_bf16(afr[mi], bfr[ni], acc[mi][ni], 0, 0, 0);
    __syncthreads();
  }
  const int cl = lane & 15, rq = (lane >> 4) * 4;
#pragma unroll
  for (int mi = 0; mi < 4; ++mi)
#pragma unroll
    for (int ni = 0; ni < 4; ++ni) {
      long col = tile_n + wn + ni * 16 + cl;
#pragma unroll
      for (int r = 0; r < 4; ++r) {
        long row = tile_m + wm + mi * 16 + rq + r;
        Cbf[(size_t)row * Ncols + col] = f2bf(acc[mi][ni][r]);
      }
    }
}

// ---- MX-fp8 NT GEMM, 128x128 tile, 4 waves, occupancy-first ------------------
// C[m,n] = (2^(sA-127))(2^(sB-127)) sum_k A[m,k]B[n,k]
// Diagnosis (rounds 0-5): waves/SIMD is capped by COMBINED VGPR+AGPR (gfx950
// unified file). 256-tile designs (acc=128 AGPR) fit only 2 waves/SIMD = ONE
// lockstep block/CU -> no independent stream to fill MFMA gaps -> util pinned
// ~29% regardless of schedule. This version: acc[4][4]=64 AGPR + trimmed VGPR
// liveness (per-mi A-frag reads) -> ~150-160 combined -> 3 waves/SIMD,
// 3 independent blocks/CU at different phases (m114 overlap).
// A: staged via global_load_lds, verified MX XOR swizzle, 2x16KB dbuf.
// B: fragment-packed (bpack), direct global->reg coalesced dwordx4 (L2-hot).
// Per K-tile: vmcnt(0) [stageA(t), full-tile lead] ; barrier ; B loads ;
//             issue stageA(t+1) ; {per mi: 2 ds_read_b128 ; 4 mfma}.
template <int OUTMODE>  // 0: bf16 C   1: fp32 C + bias
__global__ __launch_bounds__(256) void gemm_mx(const unsigned char* __restrict__ A,
                                               const unsigned char* __restrict__ Bm,
                                               unsigned short* __restrict__ Cbf,
                                               float* __restrict__ Cf,
                                               const float* __restrict__ bias,
                                               int K, int Ncols, int sA, int sB) {
  __shared__ unsigned char lds[32768];     // 2 x 16KB A double buffer

  const int tid = threadIdx.x;
  const int wave = tid >> 6, lane = tid & 63;
  const int wm = (wave >> 1) * 64, wn = (wave & 1) * 64;
  const int tile_m = blockIdx.y * 128, tile_n = blockIdx.x * 128;

  f32x4 acc[4][4] = {};

  // A staging: per K-tile, 4 chunks of 16B per thread (swizzle on global side)
  unsigned offA[4];
#pragma unroll
  for (int j = 0; j < 4; ++j) {
    int ci = j * 256 + tid;                 // 16B-chunk index in [0,1024)
    int qgs = ci >> 8, id = ci & 255;
    int r2 = (id >> 3) & 1, r3 = (id >> 4) & 1;
    int rr0 = ((id >> 1) & 1) ^ r2, rr1 = ((id >> 2) & 1) ^ r3;
    int row = rr0 | (rr1 << 1) | (r2 << 2) | (r3 << 3) | ((id >> 5) << 4);
    int half = (id & 1) ^ rr0;
    offA[j] = (unsigned)((tile_m + row) * K + qgs * 32 + half * 16);
  }

  const int hl = lane & 15, qg = lane >> 4;
  const int swz = (hl & 12) << 3;
  const int laneFragBase = qg * 4096 + ((hl * 32) ^ swz) + ((hl & 1) << 4);

  // packed-B: wave's N-half starts at row-group (tile_n+wn)>>4; lane-coalesced
  const unsigned char* gB = Bm + (size_t)((tile_n + wn) >> 4) * 16384 + (size_t)lane * 16;

  auto stageA = [&](int kt, unsigned char* dA) {
#pragma unroll
    for (int j = 0; j < 4; ++j)
      __builtin_amdgcn_global_load_lds(
          (const __attribute__((address_space(1))) void*)(A + offA[j] + kt),
          (__attribute__((address_space(3))) void*)(dA + (j * 256 + wave * 64) * 16), 16, 0, 0);
  };

  const int NT = K >> 7;
  stageA(0, lds);                           // prologue: tile 0's A

  for (int t = 0; t < NT; ++t) {
    unsigned char* bA = lds + (t & 1) * 16384;

    asm volatile("s_waitcnt vmcnt(0)" ::: "memory");  // A-stage(t) landed
    __builtin_amdgcn_s_barrier();                     // all waves left buf[(t+1)&1]

    // B(t) fragments: 8 coalesced dwordx4 from L2 (counted waits by compiler,
    // since the 4 stageA loads issued below keep vmcnt > 0 until next iter)
    const int kt16 = t * 2048;              // (kt>>7)*2048
    int8v bfr[4];
#pragma unroll
    for (int ni = 0; ni < 4; ++ni) {
      const unsigned char* bp = gB + (size_t)ni * 16384 + kt16;
      int4 h0 = *(const int4*)bp;           // half 0
      int4 h1 = *(const int4*)(bp + 1024);  // half 1
      bfr[ni] = int8v{h0.x, h0.y, h0.z, h0.w, h1.x, h1.y, h1.z, h1.w};
    }

    if (t + 1 < NT)                         // prefetch next A (full-tile lead)
      stageA((t + 1) << 7, lds + ((t + 1) & 1) * 16384);

    __builtin_amdgcn_s_setprio(1);
#pragma unroll
    for (int mi = 0; mi < 4; ++mi) {        // per-mi frag read: low VGPR liveness
      int ad = (wm + mi * 16) * 32 + laneFragBase;
      int4 h0 = *(const int4*)(bA + ad);
      int4 h1 = *(const int4*)(bA + (ad ^ 16));
      int8v af = int8v{h0.x, h0.y, h0.z, h0.w, h1.x, h1.y, h1.z, h1.w};
#pragma unroll
      for (int ni = 0; ni < 4; ++ni)
        acc[mi][ni] = __builtin_amdgcn_mfma_scale_f32_16x16x128_f8f6f4(
            af, bfr[ni], acc[mi][ni], 0, 0, 0, sA, 0, sB);
    }
    __builtin_amdgcn_s_setprio(0);
  }

  const int cl = lane & 15, rq = (lane >> 4) * 4;
#pragma unroll
  for (int mi = 0; mi < 4; ++mi)
#pragma unroll
    for (int ni = 0; ni < 4; ++ni) {
      long col = tile_n + wn + ni * 16 + cl;
      float bv = (OUTMODE == 1) ? bias[col] : 0.f;
#pragma unroll
      for (int r = 0; r < 4; ++r) {
        long row = tile_m + wm + mi * 16 + rq + r;
        if (OUTMODE == 0)
          Cbf[(size_t)row * Ncols + col] = f2bf(acc[mi][ni][r]);
        else
          Cf[(size_t)row * Ncols + col] = acc[mi][ni][r] + bv;
      }
    }
}

// ---- MFMA attention: 1 wave = 1 batch; attn_sel from accurate bf16 q1/k2 -----
__global__ __launch_bounds__(256) void attn_mfma_k(const unsigned short* __restrict__ qkv,
                                                   const unsigned short* __restrict__ q1,
                                                   const unsigned short* __restrict__ k2,
                                                   const float* __restrict__ WE,
                                                   const float* __restrict__ WF,
                                                   unsigned char* __restrict__ hmid8,
                                                   float* __restrict__ attn_sel) {
  __shared__ float As[4][16 * 17 + 2];
  const int tid = threadIdx.x;
  const int wave = tid >> 6, lane = tid & 63;
  const int b = blockIdx.x * 4 + wave;
  const size_t qb = (size_t)b * 4 * N1_;
  const int hl = lane & 15, qg = lane >> 4;

  // S[n][m] products (fp8-derived qkv: fine, softmax path is insensitive)
  f32x4 accS[4][4] = {};
  f32x4 accSel = {};
#pragma unroll
  for (int ch = 0; ch < 2; ++ch) {
    const int off = ch * 32 + qg * 8;
    short8 qf[4], kf[4];
#pragma unroll
    for (int n = 0; n < 4; ++n)
      qf[n] = *(const short8*)(qkv + qb + (size_t)n * N1_ + 0 + hl * 64 + off);
#pragma unroll
    for (int m = 0; m < 4; ++m)
      kf[m] = *(const short8*)(qkv + qb + (size_t)m * N1_ + 1024 + hl * 64 + off);
#pragma unroll
    for (int n = 0; n < 4; ++n)
#pragma unroll
      for (int m = 0; m < 4; ++m)
        accS[n][m] = __builtin_amdgcn_mfma_f32_16x16x32_bf16(qf[n], kf[m], accS[n][m], 0, 0, 0);
    // accurate attn_sel from bf16 fixup rows
    short8 qs = *(const short8*)(q1 + (size_t)b * 1024 + hl * 64 + off);
    short8 ks = *(const short8*)(k2 + (size_t)b * 1024 + hl * 64 + off);
    accSel = __builtin_amdgcn_mfma_f32_16x16x32_bf16(qs, ks, accSel, 0, 0, 0);
  }

#pragma unroll
  for (int r = 0; r < 4; ++r)
    attn_sel[(size_t)b * 256 + (qg * 4 + r) * 16 + hl] = 1.f / (1.f + __expf(-accSel[r]));

  if ((hl >> 2) == qg) {   // diagonal lanes: per-head softmax + A' = attn.WF
    const int h = hl, rr = h & 3;
    float Sm[4][4];
#pragma unroll
    for (int n = 0; n < 4; ++n)
#pragma unroll
      for (int m = 0; m < 4; ++m) Sm[n][m] = accS[n][m][rr];
#pragma unroll
    for (int n = 0; n < 4; ++n) {
      float lg[4];
#pragma unroll
      for (int p = 0; p < 4; ++p)
        lg[p] = Sm[n][0] * WE[p * 4] + Sm[n][1] * WE[p * 4 + 1] +
                Sm[n][2] * WE[p * 4 + 2] + Sm[n][3] * WE[p * 4 + 3];
      float mx = fmaxf(fmaxf(lg[0], lg[1]), fmaxf(lg[2], lg[3]));
      float e0 = __expf(lg[0] - mx), e1 = __expf(lg[1] - mx);
      float e2 = __expf(lg[2] - mx), e3 = __expf(lg[3] - mx);
      float inv = 1.f / (e0 + e1 + e2 + e3);
      e0 *= inv; e1 *= inv; e2 *= inv; e3 *= inv;
#pragma unroll
      for (int m = 0; m < 4; ++m)
        As[wave][h * 17 + n * 4 + m] =
            e0 * WF[0 * 4 + m] + e1 * WF[1 * 4 + m] + e2 * WF[2 * 4 + m] + e3 * WF[3 * 4 + m];
    }
  }
  __syncthreads();

  {  // out[h,n,d] = sum_m A'[n,m] v[h,m,d]; write hmid as fp8 x32 (scale 122)
    const int h = lane & 15, dg = lane >> 4;
    float Ap[4][4];
#pragma unroll
    for (int n = 0; n < 4; ++n)
#pragma unroll
      for (int m = 0; m < 4; ++m) Ap[n][m] = As[wave][h * 17 + n * 4 + m];

    float outv[4][16] = {};
#pragma unroll
    for (int m = 0; m < 4; ++m) {
      const unsigned short* vp = qkv + qb + (size_t)m * N1_ + 2048 + h * 64 + dg * 16;
      short8 v0 = *(const short8*)(vp);
      short8 v1 = *(const short8*)(vp + 8);
      float vf[16];
#pragma unroll
      for (int j = 0; j < 8; ++j) {
        vf[j] = bf2f((unsigned short)v0[j]);
        vf[8 + j] = bf2f((unsigned short)v1[j]);
      }
#pragma unroll
      for (int n = 0; n < 4; ++n)
#pragma unroll
        for (int d = 0; d < 16; ++d) outv[n][d] += Ap[n][m] * vf[d];
    }
#pragma unroll
    for (int n = 0; n < 4; ++n) {
      int w0 = pk_fp8(outv[n][0] * 32.f, outv[n][1] * 32.f, outv[n][2] * 32.f, outv[n][3] * 32.f);
      int w1 = pk_fp8(outv[n][4] * 32.f, outv[n][5] * 32.f, outv[n][6] * 32.f, outv[n][7] * 32.f);
      int w2 = pk_fp8(outv[n][8] * 32.f, outv[n][9] * 32.f, outv[n][10] * 32.f, outv[n][11] * 32.f);
      int w3 = pk_fp8(outv[n][12] * 32.f, outv[n][13] * 32.f, outv[n][14] * 32.f, outv[n][15] * 32.f);
      *(int4*)(hmid8 + ((size_t)b * 4 + n) * 1024 + h * 64 + dg * 16) = make_int4(w0, w1, w2, w3);
    }
  }
}

// ---- launch ------------------------------------------------------------------
extern "C" void kernel_launch(void* const* d_in, const int* in_sizes, int n_in,
                              void* d_out, int out_size, void* d_ws, size_t ws_size,
                              hipStream_t stream) {
  (void)in_sizes; (void)n_in; (void)out_size; (void)ws_size;
  const float* x      = (const float*)d_in[0];
  const float* W_qkv  = (const float*)d_in[1];
  const float* W_proj = (const float*)d_in[2];
  const float* b_proj = (const float*)d_in[3];
  const float* W_E    = (const float*)d_in[4];
  const float* W_F    = (const float*)d_in[5];

  float* out0 = (float*)d_out;                     // [B,N,C] fp32
  float* out1 = out0 + (size_t)M_ * C_;            // [B,H,H] fp32

  char* ws = (char*)d_ws;
  // Region 0 (201.3 MB): early = xsel(33.5M) + wqkvT_bf(6.3M); later = qkv_bf.
  unsigned short* xsel   = (unsigned short*)(ws);
  unsigned short* wqkvTb = (unsigned short*)(ws + 33554432);
  unsigned short* qkv_bf = (unsigned short*)(ws);               // overwrites after fixup
  unsigned char*  x8     = (unsigned char*)(ws + 201326592);    // 33.5M; hmid8 aliases it
  unsigned char*  hmid8  = x8;
  unsigned char*  wqkvT8 = (unsigned char*)(ws + 234881024);    // 3.1M (fragment-packed)
  unsigned char*  wproj8 = (unsigned char*)(ws + 238026752);    // 1.0M (fragment-packed)
  unsigned short* q1k2   = (unsigned short*)(ws + 239075328);   // 33.5M (end 272.6M)

  cast_x_k<<<32768, 256, 0, stream>>>(x, x8, xsel);
  transpose_wqkv_k<<<dim3(96, 32), dim3(32, 8), 0, stream>>>(W_qkv, wqkvTb, wqkvT8);
  cast_wproj_k<<<1024, 256, 0, stream>>>(W_proj, wproj8);

  // accurate rows for attn_sel: q1 (rows 0..8191), k2 (rows 8192..16383)
  gemm_fixup<<<dim3(8, 128), 256, 0, stream>>>(xsel, wqkvTb, q1k2);

  // GEMM1: qkv = x @ W_qkv (MX-fp8; A scale 1.0, B x32 -> scale 122)
  gemm_mx<0><<<dim3(24, 256), 256, 0, stream>>>(x8, wqkvT8, qkv_bf, nullptr, nullptr,
                                                1024, 3072, 127, 122);

  attn_mfma_k<<<B_ / 4, 256, 0, stream>>>(qkv_bf, q1k2, q1k2 + (size_t)8192 * 1024,
                                          W_E, W_F, hmid8, out1);

  // GEMM2: out = hmid @ W_proj^T + b (both fp8 x32 -> scales 122,122)
  gemm_mx<1><<<dim3(8, 256), 256, 0, stream>>>(hmid8, wproj8, nullptr, out0, b_proj,
                                               1024, 1024, 122, 122);
}

// Round 7
// 546.707 us; speedup vs baseline: 1.2684x; 1.0006x over previous
//
#include <hip/hip_runtime.h>
#include <hip/hip_bf16.h>

// Problem constants
#define B_   8192
#define C_   1024
#define H_   16
#define M_   (B_ * 4)      // 32768 rows
#define K_   1024
#define N1_  3072          // qkv GEMM cols
// SCALE = 0.125 folded into W_qkvT q-section. fp8 weights pre-scaled x32,
// compensated by MX scale byte 122 (=2^-5).

typedef __attribute__((ext_vector_type(8))) short short8;
typedef __attribute__((ext_vector_type(4))) float f32x4;
typedef __attribute__((ext_vector_type(8))) int   int8v;

__device__ __forceinline__ unsigned short f2bf(float f) {
  union { float f; unsigned u; } v; v.f = f;
  unsigned r = v.u + 0x7fffu + ((v.u >> 16) & 1u);   // RNE
  return (unsigned short)(r >> 16);
}
__device__ __forceinline__ float bf2f(unsigned short u) {
  union { unsigned u; float f; } v; v.u = ((unsigned)u) << 16;
  return v.f;
}
__device__ __forceinline__ int pk_fp8(float a, float b, float c, float d) {
  int r = __builtin_amdgcn_cvt_pk_fp8_f32(a, b, 0, false);
  r = __builtin_amdgcn_cvt_pk_fp8_f32(c, d, r, true);
  return r;
}

// Fragment-packed B layout (producer side). For B row j, K-col c (bytes):
//   po = (j>>4)*16384 + (c>>7)*2048 + ((c>>4)&1)*1024 + ((c>>5)&3)*256
//        + (j&15)*16 + (c&15)
// so that a wave's MFMA B-fragment load for (ni, half h) is ONE coalesced
// dwordx4 at  base + (row_grp+ni)*16384 + kt*16 + h*1024 + lane*16.
__device__ __forceinline__ size_t bpack(int j, int c) {
  return (size_t)(j >> 4) * 16384 + (size_t)(c >> 7) * 2048 +
         (size_t)((c >> 4) & 1) * 1024 + (size_t)((c >> 5) & 3) * 256 +
         (size_t)(j & 15) * 16 + (size_t)(c & 15);
}

// ---- cast x: fp8 (scale 1.0) for GEMM1  +  bf16 rows n in {1,2} for fixup ----
__global__ __launch_bounds__(256) void cast_x_k(const float* __restrict__ x,
                                                unsigned char* __restrict__ x8,
                                                unsigned short* __restrict__ xsel) {
  const int row = blockIdx.x;               // 32768 rows (b*4+n)
  const int tid = threadIdx.x;
  float4 v = ((const float4*)(x + (size_t)row * 1024))[tid];
  ((int*)(x8 + (size_t)row * 1024))[tid] = pk_fp8(v.x, v.y, v.z, v.w);
  const int n = row & 3;
  if (n == 1 || n == 2) {                   // wave-uniform branch (per row)
    ushort4 o;
    o.x = f2bf(v.x); o.y = f2bf(v.y); o.z = f2bf(v.z); o.w = f2bf(v.w);
    ((ushort4*)(xsel + ((size_t)(n - 1) * 8192 + (row >> 2)) * 1024))[tid] = o;
  }
}

// ---- transpose W_qkv [1024,3072] -> [3072,1024]: bf16 (fixup B, row-major)
//      + fp8 x32 in fragment-packed layout for gemm_mx ------------------------
__global__ __launch_bounds__(256) void transpose_wqkv_k(const float* __restrict__ in,
                                                        unsigned short* __restrict__ outb,
                                                        unsigned char* __restrict__ out8) {
  __shared__ float t[32][33];
  int tx = threadIdx.x, ty = threadIdx.y;   // block (32,8)
  int j0 = blockIdx.x * 32, c0 = blockIdx.y * 32;
#pragma unroll
  for (int i = 0; i < 4; ++i)
    t[ty + i * 8][tx] = in[(size_t)(c0 + ty + i * 8) * N1_ + j0 + tx];
  __syncthreads();
#pragma unroll
  for (int i = 0; i < 4; ++i) {
    int j = j0 + ty + i * 8;
    int c = c0 + tx;
    float v = t[tx][ty + i * 8];
    if (j < 1024) v *= 0.125f;              // SCALE folded into q rows
    outb[(size_t)j * K_ + c] = f2bf(v);
    out8[bpack(j, c)] =
        (unsigned char)(__builtin_amdgcn_cvt_pk_fp8_f32(v * 32.f, v * 32.f, 0, false) & 0xff);
  }
}

// ---- cast W_proj -> fp8 x32, fragment-packed (NT GEMM uses W rows as-is) -----
__global__ __launch_bounds__(256) void cast_wproj_k(const float* __restrict__ in,
                                                    unsigned char* __restrict__ out) {
  int i = blockIdx.x * 256 + threadIdx.x;
  float4 v = ((const float4*)in)[i];
  int f = i * 4;                            // flat element index
  int j = f >> 10, c = f & 1023;            // row, col (c % 4 == 0)
  *(int*)(out + bpack(j, c)) = pk_fp8(v.x * 32.f, v.y * 32.f, v.z * 32.f, v.w * 32.f);
}

// ---- bf16 NT GEMM (m97 structure, round-0 verified) for attn_sel fixup ------
// A = xsel [16384,1024]; rows <8192 use Wq section, >=8192 use Wk section.
__global__ __launch_bounds__(256) void gemm_fixup(const unsigned short* __restrict__ A,
                                                  const unsigned short* __restrict__ B0,
                                                  unsigned short* __restrict__ Cbf) {
  __shared__ unsigned short lsA[128 * 32];
  __shared__ unsigned short lsB[128 * 32];
  const int K = 1024, Ncols = 1024;
  const int tid = threadIdx.x;
  const int wave = tid >> 6, lane = tid & 63;
  const int wm = (wave >> 1) * 64, wn = (wave & 1) * 64;
  const long tile_m = (long)blockIdx.y * 128, tile_n = (long)blockIdx.x * 128;
  const unsigned short* Bm = B0 + (tile_m >= 8192 ? (size_t)1024 * 1024 : 0);

  f32x4 acc[4][4] = {};
  const int ci0 = (wave * 2 + 0) * 64 + lane;
  const int ci1 = (wave * 2 + 1) * 64 + lane;
  const int r0 = ci0 >> 2, kc0 = (ci0 & 3) * 8;
  const int r1 = ci1 >> 2, kc1 = (ci1 & 3) * 8;
  const unsigned short* gA0 = A + (tile_m + r0) * K + kc0;
  const unsigned short* gA1 = A + (tile_m + r1) * K + kc1;
  const unsigned short* gB0 = Bm + (tile_n + r0) * K + kc0;
  const unsigned short* gB1 = Bm + (tile_n + r1) * K + kc1;
  unsigned short* dA0 = lsA + (wave * 2 + 0) * 512;
  unsigned short* dA1 = lsA + (wave * 2 + 1) * 512;
  unsigned short* dB0 = lsB + (wave * 2 + 0) * 512;
  unsigned short* dB1 = lsB + (wave * 2 + 1) * 512;
  const int r16 = lane & 15, q8 = (lane >> 4) * 8;

  for (int kt = 0; kt < K; kt += 32) {
    __builtin_amdgcn_global_load_lds((const __attribute__((address_space(1))) void*)(gA0 + kt),
                                     (__attribute__((address_space(3))) void*)dA0, 16, 0, 0);
    __builtin_amdgcn_global_load_lds((const __attribute__((address_space(1))) void*)(gA1 + kt),
                                     (__attribute__((address_space(3))) void*)dA1, 16, 0, 0);
    __builtin_amdgcn_global_load_lds((const __attribute__((address_space(1))) void*)(gB0 + kt),
                                     (__attribute__((address_space(3))) void*)dB0, 16, 0, 0);
    __builtin_amdgcn_global_load_lds((const __attribute__((address_space(1))) void*)(gB1 + kt),
                                     (__attribute__((address_space(3))) void*)dB1, 16, 0, 0);
    __syncthreads();
    short8 afr[4], bfr[4];
#pragma unroll
    for (int mi = 0; mi < 4; ++mi)
      afr[mi] = *(const short8*)&lsA[(wm + mi * 16 + r16) * 32 + q8];
#pragma unroll
    for (int ni = 0; ni < 4; ++ni)
      bfr[ni] = *(const short8*)&lsB[(wn + ni * 16 + r16) * 32 + q8];
#pragma unroll
    for (int mi = 0; mi < 4; ++mi)
#pragma unroll
      for (int ni = 0; ni < 4; ++ni)
        acc[mi][ni] = __builtin_amdgcn_mfma_f32_16x16x32_bf16(afr[mi], bfr[ni], acc[mi][ni], 0, 0, 0);
    __syncthreads();
  }
  const int cl = lane & 15, rq = (lane >> 4) * 4;
#pragma unroll
  for (int mi = 0; mi < 4; ++mi)
#pragma unroll
    for (int ni = 0; ni < 4; ++ni) {
      long col = tile_n + wn + ni * 16 + cl;
#pragma unroll
      for (int r = 0; r < 4; ++r) {
        long row = tile_m + wm + mi * 16 + rq + r;
        Cbf[(size_t)row * Ncols + col] = f2bf(acc[mi][ni][r]);
      }
    }
}

// ---- MX-fp8 NT GEMM, 128x128 tile, deep-pipelined (K=1024 hardcoded) ---------
// C[m,n] = (2^(sA-127))(2^(sB-127)) sum_k A[m,k]B[n,k]
// Diagnosis r0-r6: MfmaUtil pinned ~30% because per-iter waits put load latency
// on the critical path: vmcnt(0) drained a stage issued ~1 iter earlier (HBM
// loaded-latency ~1500-2000cy), and vmcnt FIFO semantics mean any B-wait also
// force-retires older stage loads. Fix (this version):
//  - 3 LDS A-buffers (48KB), stage issued 2 TILES ahead (lead ~2 iters).
//  - B(t) issued at END of iter t-1 (lead ~1 iter >> L2 latency); loads placed
//    after the MFMAs so only 2 B register sets are ever live.
//  - NT=8 fully unrolled (no branches in VMEM stream -> compiler emits precise
//    counted vmcnt); explicit vmcnt(12)/(8) implements "stage(t) retired,
//    stage(t+1)+B(t) still in flight" per the FIFO ledger.
// Regs: ~70 VGPR + 64 AGPR -> 3 blocks/CU (31% occ), m114-style overlap.
template <int OUTMODE>  // 0: bf16 C   1: fp32 C + bias
__global__ __launch_bounds__(256) void gemm_mx(const unsigned char* __restrict__ A,
                                               const unsigned char* __restrict__ Bm,
                                               unsigned short* __restrict__ Cbf,
                                               float* __restrict__ Cf,
                                               const float* __restrict__ bias,
                                               int Ncols, int sA, int sB) {
  __shared__ unsigned char lds[49152];     // 3 x 16KB A buffers

  const int tid = threadIdx.x;
  const int wave = tid >> 6, lane = tid & 63;
  const int wm = (wave >> 1) * 64, wn = (wave & 1) * 64;
  const int tile_m = blockIdx.y * 128, tile_n = blockIdx.x * 128;

  f32x4 acc[4][4] = {};

  // A staging: per K-tile, 4 chunks of 16B per thread (swizzle on global side)
  unsigned offA[4];
#pragma unroll
  for (int j = 0; j < 4; ++j) {
    int ci = j * 256 + tid;                 // 16B-chunk index in [0,1024)
    int qgs = ci >> 8, id = ci & 255;
    int r2 = (id >> 3) & 1, r3 = (id >> 4) & 1;
    int rr0 = ((id >> 1) & 1) ^ r2, rr1 = ((id >> 2) & 1) ^ r3;
    int row = rr0 | (rr1 << 1) | (r2 << 2) | (r3 << 3) | ((id >> 5) << 4);
    int half = (id & 1) ^ rr0;
    offA[j] = (unsigned)((tile_m + row) * K_ + qgs * 32 + half * 16);
  }

  const int hl = lane & 15, qg = lane >> 4;
  const int swz = (hl & 12) << 3;
  const int laneFragBase = qg * 4096 + ((hl * 32) ^ swz) + ((hl & 1) << 4);

  // packed-B: wave's N-half starts at row-group (tile_n+wn)>>4; lane-coalesced
  const unsigned char* gB = Bm + (size_t)((tile_n + wn) >> 4) * 16384 + (size_t)lane * 16;

  auto stageA = [&](int t) {
    unsigned char* dA = lds + (t % 3) * 16384;
    const int kt = t << 7;
#pragma unroll
    for (int j = 0; j < 4; ++j)
      __builtin_amdgcn_global_load_lds(
          (const __attribute__((address_space(1))) void*)(A + offA[j] + kt),
          (__attribute__((address_space(3))) void*)(dA + (j * 256 + wave * 64) * 16), 16, 0, 0);
  };

  int8v b[4];
  auto loadB = [&](int t) {
    const int kt16 = t * 2048;
#pragma unroll
    for (int ni = 0; ni < 4; ++ni) {
      const unsigned char* bp = gB + (size_t)ni * 16384 + kt16;
      int4 h0 = *(const int4*)bp;           // half 0
      int4 h1 = *(const int4*)(bp + 1024);  // half 1
      b[ni] = int8v{h0.x, h0.y, h0.z, h0.w, h1.x, h1.y, h1.z, h1.w};
    }
  };

  // prologue: A tiles 0,1 in flight; B(0) in flight.
  stageA(0);
  stageA(1);
  loadB(0);

#pragma unroll
  for (int t = 0; t < 8; ++t) {
    // stage(t) retired; stage(t+1)[4] + B(t)[8] may stay in flight.
    if (t < 7) asm volatile("s_waitcnt vmcnt(12)" ::: "memory");
    else       asm volatile("s_waitcnt vmcnt(8)" ::: "memory");
    __builtin_amdgcn_s_barrier();           // all waves done reading buf[(t+2)%3]
    if (t + 2 < 8) stageA(t + 2);           // 2-tile lead

    unsigned char* bA = lds + (t % 3) * 16384;
    __builtin_amdgcn_s_setprio(1);
#pragma unroll
    for (int mi = 0; mi < 4; ++mi) {        // per-mi frag read: low VGPR liveness
      int ad = (wm + mi * 16) * 32 + laneFragBase;
      int4 h0 = *(const int4*)(bA + ad);
      int4 h1 = *(const int4*)(bA + (ad ^ 16));
      int8v af = int8v{h0.x, h0.y, h0.z, h0.w, h1.x, h1.y, h1.z, h1.w};
#pragma unroll
      for (int ni = 0; ni < 4; ++ni)
        acc[mi][ni] = __builtin_amdgcn_mfma_scale_f32_16x16x128_f8f6f4(
            af, b[ni], acc[mi][ni], 0, 0, 0, sA, 0, sB);
    }
    __builtin_amdgcn_s_setprio(0);

    if (t + 1 < 8) loadB(t + 1);            // ~1 iter of lead for next B
  }

  const int cl = lane & 15, rq = (lane >> 4) * 4;
#pragma unroll
  for (int mi = 0; mi < 4; ++mi)
#pragma unroll
    for (int ni = 0; ni < 4; ++ni) {
      long col = tile_n + wn + ni * 16 + cl;
      float bv = (OUTMODE == 1) ? bias[col] : 0.f;
#pragma unroll
      for (int r = 0; r < 4; ++r) {
        long row = tile_m + wm + mi * 16 + rq + r;
        if (OUTMODE == 0)
          Cbf[(size_t)row * Ncols + col] = f2bf(acc[mi][ni][r]);
        else
          Cf[(size_t)row * Ncols + col] = acc[mi][ni][r] + bv;
      }
    }
}

// ---- MFMA attention: 1 wave = 1 batch; attn_sel from accurate bf16 q1/k2 -----
__global__ __launch_bounds__(256) void attn_mfma_k(const unsigned short* __restrict__ qkv,
                                                   const unsigned short* __restrict__ q1,
                                                   const unsigned short* __restrict__ k2,
                                                   const float* __restrict__ WE,
                                                   const float* __restrict__ WF,
                                                   unsigned char* __restrict__ hmid8,
                                                   float* __restrict__ attn_sel) {
  __shared__ float As[4][16 * 17 + 2];
  const int tid = threadIdx.x;
  const int wave = tid >> 6, lane = tid & 63;
  const int b = blockIdx.x * 4 + wave;
  const size_t qb = (size_t)b * 4 * N1_;
  const int hl = lane & 15, qg = lane >> 4;

  // S[n][m] products (fp8-derived qkv: fine, softmax path is insensitive)
  f32x4 accS[4][4] = {};
  f32x4 accSel = {};
#pragma unroll
  for (int ch = 0; ch < 2; ++ch) {
    const int off = ch * 32 + qg * 8;
    short8 qf[4], kf[4];
#pragma unroll
    for (int n = 0; n < 4; ++n)
      qf[n] = *(const short8*)(qkv + qb + (size_t)n * N1_ + 0 + hl * 64 + off);
#pragma unroll
    for (int m = 0; m < 4; ++m)
      kf[m] = *(const short8*)(qkv + qb + (size_t)m * N1_ + 1024 + hl * 64 + off);
#pragma unroll
    for (int n = 0; n < 4; ++n)
#pragma unroll
      for (int m = 0; m < 4; ++m)
        accS[n][m] = __builtin_amdgcn_mfma_f32_16x16x32_bf16(qf[n], kf[m], accS[n][m], 0, 0, 0);
    // accurate attn_sel from bf16 fixup rows
    short8 qs = *(const short8*)(q1 + (size_t)b * 1024 + hl * 64 + off);
    short8 ks = *(const short8*)(k2 + (size_t)b * 1024 + hl * 64 + off);
    accSel = __builtin_amdgcn_mfma_f32_16x16x32_bf16(qs, ks, accSel, 0, 0, 0);
  }

#pragma unroll
  for (int r = 0; r < 4; ++r)
    attn_sel[(size_t)b * 256 + (qg * 4 + r) * 16 + hl] = 1.f / (1.f + __expf(-accSel[r]));

  if ((hl >> 2) == qg) {   // diagonal lanes: per-head softmax + A' = attn.WF
    const int h = hl, rr = h & 3;
    float Sm[4][4];
#pragma unroll
    for (int n = 0; n < 4; ++n)
#pragma unroll
      for (int m = 0; m < 4; ++m) Sm[n][m] = accS[n][m][rr];
#pragma unroll
    for (int n = 0; n < 4; ++n) {
      float lg[4];
#pragma unroll
      for (int p = 0; p < 4; ++p)
        lg[p] = Sm[n][0] * WE[p * 4] + Sm[n][1] * WE[p * 4 + 1] +
                Sm[n][2] * WE[p * 4 + 2] + Sm[n][3] * WE[p * 4 + 3];
      float mx = fmaxf(fmaxf(lg[0], lg[1]), fmaxf(lg[2], lg[3]));
      float e0 = __expf(lg[0] - mx), e1 = __expf(lg[1] - mx);
      float e2 = __expf(lg[2] - mx), e3 = __expf(lg[3] - mx);
      float inv = 1.f / (e0 + e1 + e2 + e3);
      e0 *= inv; e1 *= inv; e2 *= inv; e3 *= inv;
#pragma unroll
      for (int m = 0; m < 4; ++m)
        As[wave][h * 17 + n * 4 + m] =
            e0 * WF[0 * 4 + m] + e1 * WF[1 * 4 + m] + e2 * WF[2 * 4 + m] + e3 * WF[3 * 4 + m];
    }
  }
  __syncthreads();

  {  // out[h,n,d] = sum_m A'[n,m] v[h,m,d]; write hmid as fp8 x32 (scale 122)
    const int h = lane & 15, dg = lane >> 4;
    float Ap[4][4];
#pragma unroll
    for (int n = 0; n < 4; ++n)
#pragma unroll
      for (int m = 0; m < 4; ++m) Ap[n][m] = As[wave][h * 17 + n * 4 + m];

    float outv[4][16] = {};
#pragma unroll
    for (int m = 0; m < 4; ++m) {
      const unsigned short* vp = qkv + qb + (size_t)m * N1_ + 2048 + h * 64 + dg * 16;
      short8 v0 = *(const short8*)(vp);
      short8 v1 = *(const short8*)(vp + 8);
      float vf[16];
#pragma unroll
      for (int j = 0; j < 8; ++j) {
        vf[j] = bf2f((unsigned short)v0[j]);
        vf[8 + j] = bf2f((unsigned short)v1[j]);
      }
#pragma unroll
      for (int n = 0; n < 4; ++n)
#pragma unroll
        for (int d = 0; d < 16; ++d) outv[n][d] += Ap[n][m] * vf[d];
    }
#pragma unroll
    for (int n = 0; n < 4; ++n) {
      int w0 = pk_fp8(outv[n][0] * 32.f, outv[n][1] * 32.f, outv[n][2] * 32.f, outv[n][3] * 32.f);
      int w1 = pk_fp8(outv[n][4] * 32.f, outv[n][5] * 32.f, outv[n][6] * 32.f, outv[n][7] * 32.f);
      int w2 = pk_fp8(outv[n][8] * 32.f, outv[n][9] * 32.f, outv[n][10] * 32.f, outv[n][11] * 32.f);
      int w3 = pk_fp8(outv[n][12] * 32.f, outv[n][13] * 32.f, outv[n][14] * 32.f, outv[n][15] * 32.f);
      *(int4*)(hmid8 + ((size_t)b * 4 + n) * 1024 + h * 64 + dg * 16) = make_int4(w0, w1, w2, w3);
    }
  }
}

// ---- launch ------------------------------------------------------------------
extern "C" void kernel_launch(void* const* d_in, const int* in_sizes, int n_in,
                              void* d_out, int out_size, void* d_ws, size_t ws_size,
                              hipStream_t stream) {
  (void)in_sizes; (void)n_in; (void)out_size; (void)ws_size;
  const float* x      = (const float*)d_in[0];
  const float* W_qkv  = (const float*)d_in[1];
  const float* W_proj = (const float*)d_in[2];
  const float* b_proj = (const float*)d_in[3];
  const float* W_E    = (const float*)d_in[4];
  const float* W_F    = (const float*)d_in[5];

  float* out0 = (float*)d_out;                     // [B,N,C] fp32
  float* out1 = out0 + (size_t)M_ * C_;            // [B,H,H] fp32

  char* ws = (char*)d_ws;
  // Region 0 (201.3 MB): early = xsel(33.5M) + wqkvT_bf(6.3M); later = qkv_bf.
  unsigned short* xsel   = (unsigned short*)(ws);
  unsigned short* wqkvTb = (unsigned short*)(ws + 33554432);
  unsigned short* qkv_bf = (unsigned short*)(ws);               // overwrites after fixup
  unsigned char*  x8     = (unsigned char*)(ws + 201326592);    // 33.5M; hmid8 aliases it
  unsigned char*  hmid8  = x8;
  unsigned char*  wqkvT8 = (unsigned char*)(ws + 234881024);    // 3.1M (fragment-packed)
  unsigned char*  wproj8 = (unsigned char*)(ws + 238026752);    // 1.0M (fragment-packed)
  unsigned short* q1k2   = (unsigned short*)(ws + 239075328);   // 33.5M (end 272.6M)

  cast_x_k<<<32768, 256, 0, stream>>>(x, x8, xsel);
  transpose_wqkv_k<<<dim3(96, 32), dim3(32, 8), 0, stream>>>(W_qkv, wqkvTb, wqkvT8);
  cast_wproj_k<<<1024, 256, 0, stream>>>(W_proj, wproj8);

  // accurate rows for attn_sel: q1 (rows 0..8191), k2 (rows 8192..16383)
  gemm_fixup<<<dim3(8, 128), 256, 0, stream>>>(xsel, wqkvTb, q1k2);

  // GEMM1: qkv = x @ W_qkv (MX-fp8; A scale 1.0, B x32 -> scale 122)
  gemm_mx<0><<<dim3(24, 256), 256, 0, stream>>>(x8, wqkvT8, qkv_bf, nullptr, nullptr,
                                                3072, 127, 122);

  attn_mfma_k<<<B_ / 4, 256, 0, stream>>>(qkv_bf, q1k2, q1k2 + (size_t)8192 * 1024,
                                          W_E, W_F, hmid8, out1);

  // GEMM2: out = hmid @ W_proj^T + b (both fp8 x32 -> scales 122,122)
  gemm_mx<1><<<dim3(8, 256), 256, 0, stream>>>(hmid8, wproj8, nullptr, out0, b_proj,
                                               1024, 122, 122);
}